// Round 1
// baseline (2453.444 us; speedup 1.0000x reference)
//
#include <hip/hip_runtime.h>
#include <math.h>

#define HSZ 192
#define WSZ 192
#define HWSZ (192*192)
#define NB 4
#define NC 64

// ---------------- conv3x3 64->64, NCHW, 32x32 tile, 16 co per block ----------------
template<bool RELU>
__global__ __launch_bounds__(256) void conv3x3_k(const float* __restrict__ in,
    const float* __restrict__ wgt, const float* __restrict__ bias, float* __restrict__ out) {
  const int w0 = blockIdx.x * 32, h0 = blockIdx.y * 32;
  const int b = blockIdx.z >> 2, co0 = (blockIdx.z & 3) * 16;
  const int tx = threadIdx.x, ty = threadIdx.y;
  const int tid = ty * 32 + tx;
  __shared__ float s_in[34][34];
  __shared__ __align__(16) float s_w[16][12];
  float acc[4][16];
#pragma unroll
  for (int o = 0; o < 16; ++o) {
    float bv = bias[co0 + o];
#pragma unroll
    for (int p = 0; p < 4; ++p) acc[p][o] = bv;
  }
  const float* inb = in + (size_t)b * NC * HWSZ;
  for (int ci = 0; ci < NC; ++ci) {
    const float* src = inb + (size_t)ci * HWSZ;
    for (int idx = tid; idx < 34 * 34; idx += 256) {
      int r = idx / 34, cc = idx - r * 34;
      int gh = h0 - 1 + r, gw = w0 - 1 + cc;
      s_in[r][cc] = (gh >= 0 && gh < HSZ && gw >= 0 && gw < WSZ) ? src[gh * WSZ + gw] : 0.f;
    }
    if (tid < 144) {
      int o = tid / 9, k = tid - o * 9;
      s_w[o][k] = wgt[((co0 + o) * NC + ci) * 9 + k];
    }
    __syncthreads();
    float iv[4][9];
#pragma unroll
    for (int p = 0; p < 4; ++p) {
      int hh = ty + p * 8;
      iv[p][0] = s_in[hh][tx];     iv[p][1] = s_in[hh][tx + 1];     iv[p][2] = s_in[hh][tx + 2];
      iv[p][3] = s_in[hh + 1][tx]; iv[p][4] = s_in[hh + 1][tx + 1]; iv[p][5] = s_in[hh + 1][tx + 2];
      iv[p][6] = s_in[hh + 2][tx]; iv[p][7] = s_in[hh + 2][tx + 1]; iv[p][8] = s_in[hh + 2][tx + 2];
    }
#pragma unroll
    for (int o = 0; o < 16; ++o) {
      float4 wa = *(const float4*)&s_w[o][0];
      float4 wb = *(const float4*)&s_w[o][4];
      float w8 = s_w[o][8];
#pragma unroll
      for (int p = 0; p < 4; ++p) {
        acc[p][o] += iv[p][0] * wa.x + iv[p][1] * wa.y + iv[p][2] * wa.z + iv[p][3] * wa.w
                   + iv[p][4] * wb.x + iv[p][5] * wb.y + iv[p][6] * wb.z + iv[p][7] * wb.w
                   + iv[p][8] * w8;
      }
    }
    __syncthreads();
  }
  float* ob = out + (size_t)b * NC * HWSZ;
#pragma unroll
  for (int o = 0; o < 16; ++o)
#pragma unroll
    for (int p = 0; p < 4; ++p) {
      float v = acc[p][o];
      if (RELU) v = fmaxf(v, 0.f);
      ob[(size_t)(co0 + o) * HWSZ + (h0 + ty + p * 8) * WSZ + w0 + tx] = v;
    }
}

// ---------------- offset+mask conv: concat(inter,fea) 128 -> 27, 16x16 tile ----------------
__global__ __launch_bounds__(256) void offmask_k(const float* __restrict__ inter, const float* __restrict__ fea,
    const float* __restrict__ offw, const float* __restrict__ offb,
    const float* __restrict__ maskw, const float* __restrict__ maskb, float* __restrict__ om) {
  const int w0 = blockIdx.x * 16, h0 = blockIdx.y * 16;
  const int b = blockIdx.z;
  const int tx = threadIdx.x, ty = threadIdx.y;
  const int tid = ty * 16 + tx;
  __shared__ float s_in[18][18];
  __shared__ __align__(16) float s_w[27][12];
  float acc[27];
#pragma unroll
  for (int o = 0; o < 27; ++o) acc[o] = (o < 18) ? offb[o] : maskb[o - 18];
  for (int ci = 0; ci < 128; ++ci) {
    const float* src = (ci < 64) ? inter + ((size_t)b * 64 + ci) * HWSZ
                                 : fea + ((size_t)b * 64 + (ci - 64)) * HWSZ;
    for (int idx = tid; idx < 18 * 18; idx += 256) {
      int r = idx / 18, cc = idx - r * 18;
      int gh = h0 - 1 + r, gw = w0 - 1 + cc;
      s_in[r][cc] = (gh >= 0 && gh < HSZ && gw >= 0 && gw < WSZ) ? src[gh * WSZ + gw] : 0.f;
    }
    if (tid < 243) {
      int o = tid / 9, k = tid - o * 9;
      s_w[o][k] = (o < 18) ? offw[(o * 128 + ci) * 9 + k]
                           : maskw[((o - 18) * 128 + ci) * 9 + k];
    }
    __syncthreads();
    float iv[9];
    iv[0] = s_in[ty][tx];     iv[1] = s_in[ty][tx + 1];     iv[2] = s_in[ty][tx + 2];
    iv[3] = s_in[ty + 1][tx]; iv[4] = s_in[ty + 1][tx + 1]; iv[5] = s_in[ty + 1][tx + 2];
    iv[6] = s_in[ty + 2][tx]; iv[7] = s_in[ty + 2][tx + 1]; iv[8] = s_in[ty + 2][tx + 2];
#pragma unroll
    for (int o = 0; o < 27; ++o) {
      float4 wa = *(const float4*)&s_w[o][0];
      float4 wb = *(const float4*)&s_w[o][4];
      acc[o] += iv[0] * wa.x + iv[1] * wa.y + iv[2] * wa.z + iv[3] * wa.w
              + iv[4] * wb.x + iv[5] * wb.y + iv[6] * wb.z + iv[7] * wb.w
              + iv[8] * s_w[o][8];
    }
    __syncthreads();
  }
  int h = h0 + ty, w = w0 + tx;
  size_t base = (size_t)b * 27 * HWSZ + h * WSZ + w;
#pragma unroll
  for (int o = 0; o < 27; ++o) {
    float v = acc[o];
    if (o >= 18) v = 2.f / (1.f + expf(-v));
    om[base + (size_t)o * HWSZ] = v;
  }
}

// ---------------- per (b,c) spatial mean ----------------
__global__ void mean_k(const float* __restrict__ res, float* __restrict__ mean) {
  __shared__ float s[256];
  int bc = blockIdx.x;
  const float* p = res + (size_t)bc * HWSZ;
  float sum = 0.f;
  for (int i = threadIdx.x; i < HWSZ; i += 256) sum += p[i];
  s[threadIdx.x] = sum;
  __syncthreads();
  for (int st = 128; st > 0; st >>= 1) {
    if (threadIdx.x < st) s[threadIdx.x] += s[threadIdx.x + st];
    __syncthreads();
  }
  if (threadIdx.x == 0) mean[bc] = s[0] * (1.f / HWSZ);
}

// ---------------- channel attention (tiny) ----------------
__global__ void ca_k(const float* __restrict__ mean, const float* __restrict__ w1, const float* __restrict__ b1,
                     const float* __restrict__ w2, const float* __restrict__ b2, float* __restrict__ y) {
  __shared__ float s_m[4][64];
  __shared__ float s_t[4][4];
  int tid = threadIdx.x;
  int b = tid >> 6, c = tid & 63;
  s_m[b][c] = mean[tid];
  __syncthreads();
  if (tid < 16) {
    int bb = tid >> 2, r = tid & 3;
    float s = b1[r];
    for (int cc = 0; cc < 64; ++cc) s += w1[r * 64 + cc] * s_m[bb][cc];
    s_t[bb][r] = fmaxf(s, 0.f);
  }
  __syncthreads();
  float v = b2[c];
  for (int r = 0; r < 4; ++r) v += w2[c * 4 + r] * s_t[b][r];
  y[tid] = 1.f / (1.f + expf(-v));
}

// ---------------- out1 = res*y + x, write NHWC via LDS transpose ----------------
__global__ __launch_bounds__(256) void out1_k(const float* __restrict__ res, const float* __restrict__ x,
    const float* __restrict__ y, float* __restrict__ nhwc) {
  __shared__ float s[64][65];
  __shared__ float sy[64];
  int blk = blockIdx.x;
  int b = blk / (HWSZ / 64);
  int p0 = (blk % (HWSZ / 64)) * 64;
  int tid = threadIdx.x;
  if (tid < 64) sy[tid] = y[b * 64 + tid];
  __syncthreads();
  int lane = tid & 63, grp = tid >> 6;
  for (int i = 0; i < 16; ++i) {
    int c = i * 4 + grp;
    size_t idx = ((size_t)b * 64 + c) * HWSZ + p0 + lane;
    s[c][lane] = res[idx] * sy[c] + x[idx];
  }
  __syncthreads();
  for (int i = 0; i < 16; ++i) {
    int p = i * 4 + grp;
    nhwc[((size_t)b * HWSZ + p0 + p) * 64 + lane] = s[lane][p];
  }
}

// ---------------- deform weight transpose: wt[kk][o][c] = dw[o][c][kk] ----------------
__global__ void wt_k(const float* __restrict__ dw, float* __restrict__ wt) {
  int idx = blockIdx.x * 256 + threadIdx.x;  // < 36864
  int kk = idx >> 12, rem = idx & 4095;
  wt[idx] = dw[rem * 9 + kk];
}

#define DOT(A_, B_) (A_.x * B_.x + A_.y * B_.y + A_.z * B_.z + A_.w * B_.w)

// ---------------- deformable conv + residual add, write NCHW ----------------
__global__ __launch_bounds__(256) void deform_k(const float* __restrict__ nhwc, const float* __restrict__ om,
    const float* __restrict__ wt, float* __restrict__ fin) {
  int blk = blockIdx.x;
  int b = blk / (HWSZ / 64);
  int p0 = (blk % (HWSZ / 64)) * 64;
  int tid = threadIdx.x;
  __shared__ __align__(16) float s_val[64][68];
  __shared__ __align__(16) float s_w[64][68];
  __shared__ float s_bw[4][9][64];
  __shared__ int s_pk[9][64];
  const float* omb = om + (size_t)b * 27 * HWSZ + p0;
  for (int e = tid; e < 576; e += 256) {
    int kk = e / 64, pix = e - kk * 64;
    int p = p0 + pix;
    int h = p / WSZ, w = p - h * WSZ;
    float oy = omb[(size_t)(2 * kk) * HWSZ + pix];
    float ox = omb[(size_t)(2 * kk + 1) * HWSZ + pix];
    float m2 = omb[(size_t)(18 + kk) * HWSZ + pix];
    float ys = (float)(h + kk / 3 - 1) + oy;
    float xs = (float)(w + kk % 3 - 1) + ox;
    float y0f = floorf(ys), x0f = floorf(xs);
    float wy1 = ys - y0f, wx1 = xs - x0f;
    float wy0 = 1.f - wy1, wx0 = 1.f - wx1;
    int y0 = (int)y0f, x0i = (int)x0f;
    int y1 = y0 + 1, x1 = x0i + 1;
    float vy0 = (y0 >= 0 && y0 < HSZ) ? 1.f : 0.f;
    float vx0 = (x0i >= 0 && x0i < WSZ) ? 1.f : 0.f;
    float vy1 = (y1 >= 0 && y1 < HSZ) ? 1.f : 0.f;
    float vx1 = (x1 >= 0 && x1 < WSZ) ? 1.f : 0.f;
    int y0c = min(max(y0, 0), HSZ - 1), x0c = min(max(x0i, 0), WSZ - 1);
    int y1c = min(max(y1, 0), HSZ - 1), x1c = min(max(x1, 0), WSZ - 1);
    s_bw[0][kk][pix] = wy0 * wx0 * m2 * vy0 * vx0;
    s_bw[1][kk][pix] = wy0 * wx1 * m2 * vy0 * vx1;
    s_bw[2][kk][pix] = wy1 * wx0 * m2 * vy1 * vx0;
    s_bw[3][kk][pix] = wy1 * wx1 * m2 * vy1 * vx1;
    s_pk[kk][pix] = ((y0c * WSZ + x0c) << 2) | ((y1c - y0c) << 1) | (x1c - x0c);
  }
  float acc[4][4] = {{0.f}};
  int i = tid >> 4, j = tid & 15;
  int lane = tid & 63, grp = tid >> 6;
  const float* nb = nhwc + (size_t)b * HWSZ * 64;
  for (int kk = 0; kk < 9; ++kk) {
    __syncthreads();
    for (int t = tid; t < 4096; t += 256)
      s_w[t >> 6][t & 63] = wt[kk * 4096 + t];
    for (int it = 0; it < 16; ++it) {
      int pix = it * 4 + grp;
      float w00 = s_bw[0][kk][pix], w01 = s_bw[1][kk][pix];
      float w10 = s_bw[2][kk][pix], w11 = s_bw[3][kk][pix];
      int pk = s_pk[kk][pix];
      int i00 = pk >> 2, dy = (pk >> 1) & 1, dx = pk & 1;
      const float* g = nb + (size_t)i00 * 64 + lane;
      float v = w00 * g[0] + w01 * g[dx * 64] + w10 * g[dy * (WSZ * 64)] + w11 * g[(dy * WSZ + dx) * 64];
      s_val[pix][lane] = v;
    }
    __syncthreads();
#pragma unroll
    for (int c4 = 0; c4 < 16; ++c4) {
      float4 a0 = *(const float4*)&s_val[i][c4 * 4];
      float4 a1 = *(const float4*)&s_val[i + 16][c4 * 4];
      float4 a2 = *(const float4*)&s_val[i + 32][c4 * 4];
      float4 a3 = *(const float4*)&s_val[i + 48][c4 * 4];
      float4 b0 = *(const float4*)&s_w[j][c4 * 4];
      float4 b1 = *(const float4*)&s_w[j + 16][c4 * 4];
      float4 b2 = *(const float4*)&s_w[j + 32][c4 * 4];
      float4 b3 = *(const float4*)&s_w[j + 48][c4 * 4];
      acc[0][0] += DOT(a0, b0); acc[0][1] += DOT(a0, b1); acc[0][2] += DOT(a0, b2); acc[0][3] += DOT(a0, b3);
      acc[1][0] += DOT(a1, b0); acc[1][1] += DOT(a1, b1); acc[1][2] += DOT(a1, b2); acc[1][3] += DOT(a1, b3);
      acc[2][0] += DOT(a2, b0); acc[2][1] += DOT(a2, b1); acc[2][2] += DOT(a2, b2); acc[2][3] += DOT(a2, b3);
      acc[3][0] += DOT(a3, b0); acc[3][1] += DOT(a3, b1); acc[3][2] += DOT(a3, b2); acc[3][3] += DOT(a3, b3);
    }
  }
  __syncthreads();
#pragma unroll
  for (int k = 0; k < 4; ++k)
#pragma unroll
    for (int l = 0; l < 4; ++l) {
      int pix = i + 16 * k, co = j + 16 * l;
      s_val[co][pix] = acc[k][l] + nb[(size_t)(p0 + pix) * 64 + co];
    }
  __syncthreads();
  float* fb = fin + (size_t)b * 64 * HWSZ + p0;
  for (int it = 0; it < 16; ++it) {
    int co = it * 4 + grp;
    fb[(size_t)co * HWSZ + lane] = s_val[co][lane];
  }
}

extern "C" void kernel_launch(void* const* d_in, const int* in_sizes, int n_in,
                              void* d_out, int out_size, void* d_ws, size_t ws_size,
                              hipStream_t stream) {
  (void)in_sizes; (void)n_in; (void)out_size; (void)ws_size;
  const float* x     = (const float*)d_in[0];
  const float* inter = (const float*)d_in[1];
  const float* fea   = (const float*)d_in[2];
  const float* rw1   = (const float*)d_in[3];
  const float* rb1   = (const float*)d_in[4];
  const float* rw2   = (const float*)d_in[5];
  const float* rb2   = (const float*)d_in[6];
  const float* caw1  = (const float*)d_in[7];
  const float* cab1  = (const float*)d_in[8];
  const float* caw2  = (const float*)d_in[9];
  const float* cab2  = (const float*)d_in[10];
  const float* offw  = (const float*)d_in[11];
  const float* offb  = (const float*)d_in[12];
  const float* maskw = (const float*)d_in[13];
  const float* maskb = (const float*)d_in[14];
  const float* dw    = (const float*)d_in[15];
  const float* cw    = (const float*)d_in[16];
  const float* cb    = (const float*)d_in[17];

  float* ws = (float*)d_ws;
  const size_t IMG = (size_t)NB * NC * HWSZ;  // 9437184 floats
  float* r1   = ws;                // conv1 out; later reused as deform output (fin)
  float* res  = ws + IMG;          // conv2 out; later reused as offset/mask buffer
  float* nhwc = ws + 2 * IMG;      // out1 in NHWC
  float* wt   = ws + 3 * IMG;      // 36864 floats
  float* mean = wt + 36864;        // 256
  float* yv   = mean + 256;        // 256
  float* om   = res;
  float* fin  = r1;

  dim3 cgrid(6, 6, 16), cblk(32, 8);
  conv3x3_k<true><<<cgrid, cblk, 0, stream>>>(x, rw1, rb1, r1);
  conv3x3_k<false><<<cgrid, cblk, 0, stream>>>(r1, rw2, rb2, res);
  mean_k<<<256, 256, 0, stream>>>(res, mean);
  ca_k<<<1, 256, 0, stream>>>(mean, caw1, cab1, caw2, cab2, yv);
  out1_k<<<NB * (HWSZ / 64), 256, 0, stream>>>(res, x, yv, nhwc);
  offmask_k<<<dim3(12, 12, NB), dim3(16, 16), 0, stream>>>(inter, fea, offw, offb, maskw, maskb, om);
  wt_k<<<144, 256, 0, stream>>>(dw, wt);
  deform_k<<<NB * (HWSZ / 64), 256, 0, stream>>>(nhwc, om, wt, fin);
  conv3x3_k<false><<<cgrid, cblk, 0, stream>>>(fin, cw, cb, (float*)d_out);
}

// Round 2
// 796.830 us; speedup vs baseline: 3.0790x; 3.0790x over previous
//
#include <hip/hip_runtime.h>
#include <hip/hip_bf16.h>
#include <math.h>

#define HSZ 192
#define WSZ 192
#define HWSZ (192*192)
#define PH 194                 // padded dim
#define PP (PH*PH)             // 37636 padded pixels
#define NB 4

typedef __attribute__((ext_vector_type(8))) short short8;
typedef __attribute__((ext_vector_type(4))) float f32x4;

__device__ inline unsigned short f2bf(float f) { __hip_bfloat16 h = __float2bfloat16(f); return *(unsigned short*)&h; }
__device__ inline float bf2f(__hip_bfloat16 h) { return __bfloat162float(h); }

#define GLDS(SRC, DST) __builtin_amdgcn_global_load_lds( \
    (const __attribute__((address_space(1))) unsigned int*)(const void*)(SRC), \
    (__attribute__((address_space(3))) unsigned int*)(void*)(DST), 16, 0, 0)

#define MFMA(A,B,C) __builtin_amdgcn_mfma_f32_16x16x32_bf16((A),(B),(C),0,0,0)

// ------------- zero padded-border of an NHWC buffer -------------
__global__ void zb_k(__hip_bfloat16* buf, int Cn) {
  int idx = blockIdx.x * 256 + threadIdx.x;
  int cg8 = Cn >> 3;
  int tot = NB * 772 * cg8;
  if (idx >= tot) return;
  int cg = idx % cg8; int rem = idx / cg8;
  int e = rem % 772; int b = rem / 772;
  int h, w2;
  if (e < 194) { h = 0; w2 = e; }
  else if (e < 388) { h = 193; w2 = e - 194; }
  else if (e < 580) { h = e - 388 + 1; w2 = 0; }
  else { h = e - 580 + 1; w2 = 193; }
  uint4 z = make_uint4(0, 0, 0, 0);
  *(uint4*)&buf[(((size_t)b * PH + h) * PH + w2) * Cn + cg * 8] = z;
}

// ------------- NCHW f32 -> padded NHWC bf16 (64-channel group) -------------
__global__ __launch_bounds__(256) void nchw2nhwc_k(const float* __restrict__ src,
    __hip_bfloat16* __restrict__ dst, int Cdst, int coff) {
  __shared__ float s[64][65];
  int p0 = blockIdx.x * 64; int b = blockIdx.y;
  int lane = threadIdx.x & 63, g = threadIdx.x >> 6;
#pragma unroll
  for (int i = 0; i < 16; ++i) {
    int c = i * 4 + g;
    s[c][lane] = src[((size_t)b * 64 + c) * HWSZ + p0 + lane];
  }
  __syncthreads();
  int h = p0 / WSZ, w0 = p0 - h * WSZ;
  size_t base = ((size_t)b * PH + h + 1) * PH + 1 + w0;
#pragma unroll
  for (int i = 0; i < 16; ++i) {
    int pp = i * 4 + g;
    dst[(base + pp) * Cdst + coff + lane] = __float2bfloat16(s[lane][pp]);
  }
}

// ------------- weight converters -------------
__global__ void convwt_k(const float* __restrict__ src, short* __restrict__ dst) {
  int idx = blockIdx.x * 256 + threadIdx.x;   // 36864
  int kk = idx >> 12, rem = idx & 4095;
  int co = rem >> 6, ci = rem & 63;
  dst[idx] = (short)f2bf(src[(co * 64 + ci) * 9 + kk]);
}
__global__ void omwt_k(const float* __restrict__ offw, const float* __restrict__ maskw,
                       const float* __restrict__ offb, const float* __restrict__ maskb,
                       short* __restrict__ dst, float* __restrict__ ob) {
  int idx = blockIdx.x * 256 + threadIdx.x;   // 36864 = 9*32*128
  int kk = idx >> 12, rem = idx & 4095;
  int co = rem >> 7, ci = rem & 127;
  float v = 0.f;
  if (co < 18) v = offw[(co * 128 + ci) * 9 + kk];
  else if (co < 27) v = maskw[((co - 18) * 128 + ci) * 9 + kk];
  dst[idx] = (short)f2bf(v);
  if (idx < 32) ob[idx] = idx < 18 ? offb[idx] : (idx < 27 ? maskb[idx - 18] : 0.f);
}
__global__ void dwt_k(const float* __restrict__ dw, float* __restrict__ wtd) {
  int idx = blockIdx.x * 256 + threadIdx.x;   // 36864
  int kk = idx >> 12, rem = idx & 4095;
  wtd[idx] = dw[rem * 9 + kk];
}

// ------------- MFMA conv3x3 64->64 over padded NHWC bf16 -------------
// OUT_MODE 0: swapped operands, NHWC bf16 out (LDS transpose epilogue)
// OUT_MODE 1: normal operands, NCHW f32 out (direct stores)
template<int OUT_MODE, bool RELU>
__global__ __launch_bounds__(256, 2) void conv_mfma_k(
    const __hip_bfloat16* __restrict__ inp, const short* __restrict__ wt,
    const float* __restrict__ bias, __hip_bfloat16* __restrict__ outB, float* __restrict__ outF) {
  const int h = blockIdx.x, b = blockIdx.y;
  const int tid = threadIdx.x, lane = tid & 63, wid = tid >> 6;
  const int q = lane >> 4, r16 = lane & 15;
  __shared__ __align__(16) short tile[3 * 200 * 64];   // 76800 B

  // stage padded rows h..h+2, 200 px * 128B each, swizzled source -> linear LDS
  {
    const char* gb = (const char*)(inp + ((size_t)b * PH + h) * (PH * 64));
    for (int s = wid; s < 75; s += 4) {
      int rr = s / 25, si = s - rr * 25;
      int pix = 8 * si + (lane >> 3);
      const char* src = gb + (size_t)rr * (PH * 128) + pix * 128
                      + ((((lane & 7) ^ ((lane >> 3) & 7))) << 4);
      GLDS(src, tile + rr * 12800 + si * 512);
    }
  }

  f32x4 acc[3][4];
  if (OUT_MODE == 0) {
#pragma unroll
    for (int nf = 0; nf < 4; ++nf) {
      float4 bv = *(const float4*)&bias[nf * 16 + q * 4];
      f32x4 v; v[0] = bv.x; v[1] = bv.y; v[2] = bv.z; v[3] = bv.w;
      acc[0][nf] = v; acc[1][nf] = v; acc[2][nf] = v;
    }
  } else {
#pragma unroll
    for (int nf = 0; nf < 4; ++nf) {
      float bs = bias[nf * 16 + r16];
      f32x4 v; v[0] = bs; v[1] = bs; v[2] = bs; v[3] = bs;
      acc[0][nf] = v; acc[1][nf] = v; acc[2][nf] = v;
    }
  }
  __syncthreads();

  const int wm0 = wid * 48;
  for (int kk = 0; kk < 9; ++kk) {
    const int ky = kk / 3, kx = kk - ky * 3;
    short8 bfr[2][4];
    const short* wk = wt + kk * 4096 + r16 * 64 + q * 8;
#pragma unroll
    for (int nf = 0; nf < 4; ++nf) {
      bfr[0][nf] = *(const short8*)(wk + nf * 1024);
      bfr[1][nf] = *(const short8*)(wk + nf * 1024 + 32);
    }
#pragma unroll
    for (int mf = 0; mf < 3; ++mf) {
      int pix = wm0 + mf * 16 + r16 + kx;
      const char* ab = (const char*)tile + ky * 25600 + pix * 128;
      int sw = (pix & 7) << 4;
      short8 a0 = *(const short8*)(ab + ((q << 4) ^ sw));
      short8 a1 = *(const short8*)(ab + (((q + 4) << 4) ^ sw));
#pragma unroll
      for (int nf = 0; nf < 4; ++nf) {
        if (OUT_MODE == 0) {
          acc[mf][nf] = MFMA(bfr[0][nf], a0, acc[mf][nf]);
          acc[mf][nf] = MFMA(bfr[1][nf], a1, acc[mf][nf]);
        } else {
          acc[mf][nf] = MFMA(a0, bfr[0][nf], acc[mf][nf]);
          acc[mf][nf] = MFMA(a1, bfr[1][nf], acc[mf][nf]);
        }
      }
    }
  }

  if (OUT_MODE == 0) {
    __syncthreads();
#pragma unroll
    for (int mf = 0; mf < 3; ++mf)
#pragma unroll
      for (int nf = 0; nf < 4; ++nf) {
        f32x4 v = acc[mf][nf];
        if (RELU) { v[0] = fmaxf(v[0], 0.f); v[1] = fmaxf(v[1], 0.f); v[2] = fmaxf(v[2], 0.f); v[3] = fmaxf(v[3], 0.f); }
        unsigned lo = (unsigned)f2bf(v[0]) | ((unsigned)f2bf(v[1]) << 16);
        unsigned hi = (unsigned)f2bf(v[2]) | ((unsigned)f2bf(v[3]) << 16);
        int pix = wm0 + mf * 16 + r16;           // swapped: lane col = pixel
        int byteoff = (pix * 128 + nf * 32 + q * 8) ^ ((pix & 7) << 4);
        *(uint2*)((char*)tile + byteoff) = make_uint2(lo, hi);
      }
    __syncthreads();
    char* orow = (char*)outB + ((((size_t)b * PH + h + 1) * PH + 1) * 64) * 2;
    for (int s = wid; s < 24; s += 4) {
      int pix = 8 * s + (lane >> 3);
      int g16 = ((lane & 7) ^ (pix & 7)) << 4;
      uint4 d = *(const uint4*)((const char*)tile + pix * 128 + g16);
      *(uint4*)(orow + pix * 128 + ((lane & 7) << 4)) = d;
    }
  } else {
    float* ob2 = outF + (size_t)b * 64 * HWSZ + h * WSZ;
#pragma unroll
    for (int mf = 0; mf < 3; ++mf)
#pragma unroll
      for (int nf = 0; nf < 4; ++nf) {
        int pix0 = wm0 + mf * 16 + q * 4;
        int co = nf * 16 + r16;
        *(f32x4*)&ob2[(size_t)co * HWSZ + pix0] = acc[mf][nf];
      }
  }
}

// ------------- MFMA offset+mask conv: 128 -> 27(pad 32), NCHW f32 out -------------
__global__ __launch_bounds__(256, 3) void offmask_mfma_k(
    const __hip_bfloat16* __restrict__ cat, const short* __restrict__ wt2,
    const float* __restrict__ ob, float* __restrict__ om) {
  const int h = blockIdx.x, b = blockIdx.y;
  const int tid = threadIdx.x, lane = tid & 63, wid = tid >> 6;
  const int q = lane >> 4, r16 = lane & 15;
  __shared__ __align__(16) short tile[200 * 128];      // 51200 B

  f32x4 acc[3][2];
#pragma unroll
  for (int nf = 0; nf < 2; ++nf) {
    float bs = ob[nf * 16 + r16];
    f32x4 v; v[0] = bs; v[1] = bs; v[2] = bs; v[3] = bs;
    acc[0][nf] = v; acc[1][nf] = v; acc[2][nf] = v;
  }
  const char* gb = (const char*)(cat + ((size_t)b * PH + h) * (PH * 128));
  const int wm0 = wid * 48;

  for (int r = 0; r < 3; ++r) {
    __syncthreads();
    for (int s = wid; s < 50; s += 4) {
      int pix = 4 * s + (lane >> 4);
      const char* src = gb + (size_t)r * (PH * 256) + pix * 256
                      + ((((lane & 15) ^ (pix & 15))) << 4);
      GLDS(src, tile + s * 512);
    }
    __syncthreads();
    for (int kx = 0; kx < 3; ++kx) {
      int kk = r * 3 + kx;
      short8 bfr[4][2];
      const short* wk = wt2 + kk * 4096 + r16 * 128 + q * 8;
#pragma unroll
      for (int c4 = 0; c4 < 4; ++c4) {
        bfr[c4][0] = *(const short8*)(wk + c4 * 32);
        bfr[c4][1] = *(const short8*)(wk + 2048 + c4 * 32);
      }
#pragma unroll
      for (int mf = 0; mf < 3; ++mf) {
        int pix = wm0 + mf * 16 + r16 + kx;
        const char* ab = (const char*)tile + pix * 256;
        int sw = (pix & 15) << 4;
        short8 a0 = *(const short8*)(ab + ((q << 4) ^ sw));
        short8 a1 = *(const short8*)(ab + (((4 + q) << 4) ^ sw));
        short8 a2 = *(const short8*)(ab + (((8 + q) << 4) ^ sw));
        short8 a3 = *(const short8*)(ab + (((12 + q) << 4) ^ sw));
        acc[mf][0] = MFMA(a0, bfr[0][0], acc[mf][0]); acc[mf][1] = MFMA(a0, bfr[0][1], acc[mf][1]);
        acc[mf][0] = MFMA(a1, bfr[1][0], acc[mf][0]); acc[mf][1] = MFMA(a1, bfr[1][1], acc[mf][1]);
        acc[mf][0] = MFMA(a2, bfr[2][0], acc[mf][0]); acc[mf][1] = MFMA(a2, bfr[2][1], acc[mf][1]);
        acc[mf][0] = MFMA(a3, bfr[3][0], acc[mf][0]); acc[mf][1] = MFMA(a3, bfr[3][1], acc[mf][1]);
      }
    }
  }
#pragma unroll
  for (int mf = 0; mf < 3; ++mf)
#pragma unroll
    for (int nf = 0; nf < 2; ++nf) {
      int co = nf * 16 + r16;
      if (co < 27) {
        f32x4 v = acc[mf][nf];
        if (co >= 18) {
          v[0] = 2.f / (1.f + expf(-v[0])); v[1] = 2.f / (1.f + expf(-v[1]));
          v[2] = 2.f / (1.f + expf(-v[2])); v[3] = 2.f / (1.f + expf(-v[3]));
        }
        *(f32x4*)&om[((size_t)(b * 27 + co)) * HWSZ + h * WSZ + wm0 + mf * 16 + q * 4] = v;
      }
    }
}

// ------------- per (b,c) spatial mean over padded NHWC bf16 -------------
__global__ __launch_bounds__(256) void mean_k(const __hip_bfloat16* __restrict__ res, float* __restrict__ mean) {
  int blk = blockIdx.x;                 // 128 = 4 b * 32 slices
  int b = blk >> 5, slice = blk & 31;
  int c = threadIdx.x & 63, g = threadIdx.x >> 6;
  const __hip_bfloat16* rb = res + (size_t)b * PP * 64;
  float sum = 0.f;
  for (int i = g; i < 1152; i += 4) {
    int p = slice * 1152 + i;
    int hh = p / WSZ, ww = p - hh * WSZ;
    sum += bf2f(rb[((size_t)(hh + 1) * PH + ww + 1) * 64 + c]);
  }
  __shared__ float sm[4][64];
  sm[g][c] = sum; __syncthreads();
  if (threadIdx.x < 64)
    atomicAdd(&mean[b * 64 + threadIdx.x],
              (sm[0][threadIdx.x] + sm[1][threadIdx.x] + sm[2][threadIdx.x] + sm[3][threadIdx.x]) * (1.f / 36864.f));
}

// ------------- channel attention (tiny) -------------
__global__ void ca_k(const float* __restrict__ mean, const float* __restrict__ w1, const float* __restrict__ b1,
                     const float* __restrict__ w2, const float* __restrict__ b2, float* __restrict__ y) {
  __shared__ float s_m[4][64];
  __shared__ float s_t[4][4];
  int tid = threadIdx.x;
  int b = tid >> 6, c = tid & 63;
  s_m[b][c] = mean[tid];
  __syncthreads();
  if (tid < 16) {
    int bb = tid >> 2, r = tid & 3;
    float s = b1[r];
    for (int cc = 0; cc < 64; ++cc) s += w1[r * 64 + cc] * s_m[bb][cc];
    s_t[bb][r] = fmaxf(s, 0.f);
  }
  __syncthreads();
  float v = b2[c];
  for (int r = 0; r < 4; ++r) v += w2[c * 4 + r] * s_t[b][r];
  y[tid] = 1.f / (1.f + expf(-v));
}

// ------------- out1 = res*y + x (elementwise, padded NHWC bf16) -------------
__global__ __launch_bounds__(256) void out1_k(const __hip_bfloat16* __restrict__ res, const __hip_bfloat16* __restrict__ xn,
    const float* __restrict__ y, __hip_bfloat16* __restrict__ out1) {
  int idx = blockIdx.x * 256 + threadIdx.x;     // 4*36864*8
  int b = idx / 294912; int rem = idx - b * 294912;
  int p = rem >> 3, c8 = rem & 7;
  int hh = p / WSZ, ww = p - hh * WSZ;
  size_t off = ((size_t)b * PP + (size_t)(hh + 1) * PH + ww + 1) * 64 + c8 * 8;
  const __hip_bfloat16* rp = res + off;
  const __hip_bfloat16* xp = xn + off;
  __hip_bfloat16* op = out1 + off;
  const float* yb = y + b * 64 + c8 * 8;
  unsigned pk[4];
#pragma unroll
  for (int t = 0; t < 4; ++t) {
    float v0 = bf2f(rp[2 * t]) * yb[2 * t] + bf2f(xp[2 * t]);
    float v1 = bf2f(rp[2 * t + 1]) * yb[2 * t + 1] + bf2f(xp[2 * t + 1]);
    pk[t] = (unsigned)f2bf(v0) | ((unsigned)f2bf(v1) << 16);
  }
  *(uint4*)op = make_uint4(pk[0], pk[1], pk[2], pk[3]);
}

#define DOT(A_, B_) (A_.x * B_.x + A_.y * B_.y + A_.z * B_.z + A_.w * B_.w)

// ------------- deformable conv + residual add: padded NHWC bf16 in/out -------------
__global__ __launch_bounds__(256) void deform_k(const __hip_bfloat16* __restrict__ nhwc, const float* __restrict__ om,
    const float* __restrict__ wtd, __hip_bfloat16* __restrict__ fin) {
  int blk = blockIdx.x;
  int b = blk / 576;
  int p0 = (blk - b * 576) * 64;
  int tid = threadIdx.x;
  __shared__ __align__(16) float s_val[64][68];
  __shared__ __align__(16) float s_w[64][68];
  __shared__ float s_bw[4][9][64];
  __shared__ int s_pk[9][64];
  const float* omb = om + (size_t)b * 27 * HWSZ + p0;
  for (int e = tid; e < 576; e += 256) {
    int kk = e / 64, pix = e - kk * 64;
    int p = p0 + pix;
    int h = p / WSZ, w2 = p - h * WSZ;
    float oy = omb[(size_t)(2 * kk) * HWSZ + pix];
    float ox = omb[(size_t)(2 * kk + 1) * HWSZ + pix];
    float m2 = omb[(size_t)(18 + kk) * HWSZ + pix];
    float ys = (float)(h + kk / 3 - 1) + oy;
    float xs = (float)(w2 + kk % 3 - 1) + ox;
    float y0f = floorf(ys), x0f = floorf(xs);
    float wy1 = ys - y0f, wx1 = xs - x0f;
    float wy0 = 1.f - wy1, wx0 = 1.f - wx1;
    int y0 = (int)y0f, x0i = (int)x0f;
    int y1 = y0 + 1, x1 = x0i + 1;
    float vy0 = (y0 >= 0 && y0 < HSZ) ? 1.f : 0.f;
    float vx0 = (x0i >= 0 && x0i < WSZ) ? 1.f : 0.f;
    float vy1 = (y1 >= 0 && y1 < HSZ) ? 1.f : 0.f;
    float vx1 = (x1 >= 0 && x1 < WSZ) ? 1.f : 0.f;
    int y0c = min(max(y0, 0), HSZ - 1), x0c = min(max(x0i, 0), WSZ - 1);
    int y1c = min(max(y1, 0), HSZ - 1), x1c = min(max(x1, 0), WSZ - 1);
    s_bw[0][kk][pix] = wy0 * wx0 * m2 * vy0 * vx0;
    s_bw[1][kk][pix] = wy0 * wx1 * m2 * vy0 * vx1;
    s_bw[2][kk][pix] = wy1 * wx0 * m2 * vy1 * vx0;
    s_bw[3][kk][pix] = wy1 * wx1 * m2 * vy1 * vx1;
    s_pk[kk][pix] = ((((y0c + 1) * PH) + x0c + 1) << 2) | ((y1c - y0c) << 1) | (x1c - x0c);
  }
  float acc[4][4] = {{0.f}};
  int i = tid >> 4, j = tid & 15;
  int lane = tid & 63, grp = tid >> 6;
  const __hip_bfloat16* nb = nhwc + (size_t)b * PP * 64;
  for (int kk = 0; kk < 9; ++kk) {
    __syncthreads();
    for (int t = tid; t < 4096; t += 256)
      s_w[t >> 6][t & 63] = wtd[kk * 4096 + t];
    for (int it = 0; it < 16; ++it) {
      int pix = it * 4 + grp;
      float w00 = s_bw[0][kk][pix], w01 = s_bw[1][kk][pix];
      float w10 = s_bw[2][kk][pix], w11 = s_bw[3][kk][pix];
      int pk = s_pk[kk][pix];
      int i00 = pk >> 2, dy = (pk >> 1) & 1, dx = pk & 1;
      const __hip_bfloat16* g = nb + (size_t)i00 * 64 + lane;
      float v = w00 * bf2f(g[0]) + w01 * bf2f(g[dx * 64]) + w10 * bf2f(g[dy * (PH * 64)])
              + w11 * bf2f(g[(dy * PH + dx) * 64]);
      s_val[pix][lane] = v;
    }
    __syncthreads();
#pragma unroll
    for (int c4 = 0; c4 < 16; ++c4) {
      float4 a0 = *(const float4*)&s_val[i][c4 * 4];
      float4 a1 = *(const float4*)&s_val[i + 16][c4 * 4];
      float4 a2 = *(const float4*)&s_val[i + 32][c4 * 4];
      float4 a3 = *(const float4*)&s_val[i + 48][c4 * 4];
      float4 b0 = *(const float4*)&s_w[j][c4 * 4];
      float4 b1 = *(const float4*)&s_w[j + 16][c4 * 4];
      float4 b2 = *(const float4*)&s_w[j + 32][c4 * 4];
      float4 b3 = *(const float4*)&s_w[j + 48][c4 * 4];
      acc[0][0] += DOT(a0, b0); acc[0][1] += DOT(a0, b1); acc[0][2] += DOT(a0, b2); acc[0][3] += DOT(a0, b3);
      acc[1][0] += DOT(a1, b0); acc[1][1] += DOT(a1, b1); acc[1][2] += DOT(a1, b2); acc[1][3] += DOT(a1, b3);
      acc[2][0] += DOT(a2, b0); acc[2][1] += DOT(a2, b1); acc[2][2] += DOT(a2, b2); acc[2][3] += DOT(a2, b3);
      acc[3][0] += DOT(a3, b0); acc[3][1] += DOT(a3, b1); acc[3][2] += DOT(a3, b2); acc[3][3] += DOT(a3, b3);
    }
  }
  __syncthreads();
  int h0 = p0 / WSZ, w0 = p0 - h0 * WSZ;
  size_t ro = ((size_t)(h0 + 1) * PH + w0 + 1) * 64;
#pragma unroll
  for (int k = 0; k < 4; ++k)
#pragma unroll
    for (int l = 0; l < 4; ++l) {
      int pix = i + 16 * k, co = j + 16 * l;
      s_val[pix][co] = acc[k][l] + bf2f(nb[ro + (size_t)pix * 64 + co]);
    }
  __syncthreads();
  int pix2 = tid >> 2, qq = tid & 3;
  __hip_bfloat16* fp = fin + (size_t)b * PP * 64 + ro;
  unsigned pk8[8];
#pragma unroll
  for (int t = 0; t < 8; ++t) {
    pk8[t] = (unsigned)f2bf(s_val[pix2][qq * 16 + 2 * t]) | ((unsigned)f2bf(s_val[pix2][qq * 16 + 2 * t + 1]) << 16);
  }
  uint4* dp = (uint4*)(fp + (size_t)pix2 * 64 + qq * 16);
  dp[0] = make_uint4(pk8[0], pk8[1], pk8[2], pk8[3]);
  dp[1] = make_uint4(pk8[4], pk8[5], pk8[6], pk8[7]);
}

extern "C" void kernel_launch(void* const* d_in, const int* in_sizes, int n_in,
                              void* d_out, int out_size, void* d_ws, size_t ws_size,
                              hipStream_t stream) {
  (void)in_sizes; (void)n_in; (void)out_size; (void)ws_size;
  const float* x     = (const float*)d_in[0];
  const float* inter = (const float*)d_in[1];
  const float* fea   = (const float*)d_in[2];
  const float* rw1   = (const float*)d_in[3];
  const float* rb1   = (const float*)d_in[4];
  const float* rw2   = (const float*)d_in[5];
  const float* rb2   = (const float*)d_in[6];
  const float* caw1  = (const float*)d_in[7];
  const float* cab1  = (const float*)d_in[8];
  const float* caw2  = (const float*)d_in[9];
  const float* cab2  = (const float*)d_in[10];
  const float* offw  = (const float*)d_in[11];
  const float* offb  = (const float*)d_in[12];
  const float* maskw = (const float*)d_in[13];
  const float* maskb = (const float*)d_in[14];
  const float* dw    = (const float*)d_in[15];
  const float* cw    = (const float*)d_in[16];
  const float* cb    = (const float*)d_in[17];

  char* w = (char*)d_ws;
  const size_t P64 = (size_t)NB * PP * 64 * 2 + 4096;   // padded 64ch bf16 + slack
  const size_t PCAT = (size_t)NB * PP * 128 * 2 + 4096;
  __hip_bfloat16* xn   = (__hip_bfloat16*)(w);
  __hip_bfloat16* r1   = (__hip_bfloat16*)(w + P64);
  __hip_bfloat16* res  = (__hip_bfloat16*)(w + 2 * P64);
  __hip_bfloat16* out1 = (__hip_bfloat16*)(w + 3 * P64);
  __hip_bfloat16* cat  = (__hip_bfloat16*)(w + 4 * P64);
  char* tail = w + 4 * P64 + PCAT;
  short* wt1  = (short*)tail; tail += 73728;
  short* wt2c = (short*)tail; tail += 73728;
  short* wtf  = (short*)tail; tail += 73728;
  short* wtom = (short*)tail; tail += 73728;
  float* obb  = (float*)tail; tail += 128;
  float* wtd  = (float*)tail; tail += 147456;
  float* mean = (float*)tail; tail += 1024;
  float* yv   = (float*)tail; tail += 1024;
  float* omb  = (float*)res;        // overlay: om reuses res slot (res dead by then)
  __hip_bfloat16* fin = r1;         // overlay: fin reuses r1 slot (r1 dead by then)

  // border zeroing (per launch; deterministic)
  zb_k<<<(NB * 772 * 8 + 255) / 256, 256, 0, stream>>>(xn, 64);
  zb_k<<<(NB * 772 * 8 + 255) / 256, 256, 0, stream>>>(r1, 64);
  zb_k<<<(NB * 772 * 8 + 255) / 256, 256, 0, stream>>>(out1, 64);
  zb_k<<<(NB * 772 * 16 + 255) / 256, 256, 0, stream>>>(cat, 128);

  // layout conversions
  nchw2nhwc_k<<<dim3(576, 4), 256, 0, stream>>>(x, xn, 64, 0);
  nchw2nhwc_k<<<dim3(576, 4), 256, 0, stream>>>(inter, cat, 128, 0);
  nchw2nhwc_k<<<dim3(576, 4), 256, 0, stream>>>(fea, cat, 128, 64);
  convwt_k<<<144, 256, 0, stream>>>(rw1, wt1);
  convwt_k<<<144, 256, 0, stream>>>(rw2, wt2c);
  convwt_k<<<144, 256, 0, stream>>>(cw, wtf);
  omwt_k<<<144, 256, 0, stream>>>(offw, maskw, offb, maskb, wtom, obb);
  dwt_k<<<144, 256, 0, stream>>>(dw, wtd);

  // main pipeline
  conv_mfma_k<0, true ><<<dim3(192, 4), 256, 0, stream>>>(xn, wt1, rb1, r1, nullptr);
  conv_mfma_k<0, false><<<dim3(192, 4), 256, 0, stream>>>(r1, wt2c, rb2, res, nullptr);
  hipMemsetAsync(mean, 0, 256 * 4, stream);
  mean_k<<<128, 256, 0, stream>>>(res, mean);
  ca_k<<<1, 256, 0, stream>>>(mean, caw1, cab1, caw2, cab2, yv);
  out1_k<<<4608, 256, 0, stream>>>(res, xn, yv, out1);
  offmask_mfma_k<<<dim3(192, 4), 256, 0, stream>>>(cat, wtom, obb, omb);
  deform_k<<<NB * 576, 256, 0, stream>>>(out1, omb, wtd, fin);
  conv_mfma_k<1, false><<<dim3(192, 4), 256, 0, stream>>>(fin, wtf, cb, nullptr, (float*)d_out);
}

// Round 3
// 402.279 us; speedup vs baseline: 6.0989x; 1.9808x over previous
//
#include <hip/hip_runtime.h>
#include <hip/hip_bf16.h>
#include <math.h>

#define HSZ 192
#define WSZ 192
#define HWSZ (192*192)
#define PH 194                 // padded dim
#define PP (PH*PH)             // 37636 padded pixels
#define NB 4

typedef __attribute__((ext_vector_type(8))) short short8;
typedef __attribute__((ext_vector_type(4))) float f32x4;

__device__ inline unsigned short f2bf(float f) { __hip_bfloat16 h = __float2bfloat16(f); return *(unsigned short*)&h; }
__device__ inline float bf2f(__hip_bfloat16 h) { return __bfloat162float(h); }
__device__ inline float bflo(unsigned u) { return __uint_as_float(u << 16); }
__device__ inline float bfhi(unsigned u) { return __uint_as_float(u & 0xffff0000u); }

#define GLDS(SRC, DST) __builtin_amdgcn_global_load_lds( \
    (const __attribute__((address_space(1))) unsigned int*)(const void*)(SRC), \
    (__attribute__((address_space(3))) unsigned int*)(void*)(DST), 16, 0, 0)

#define MFMA(A,B,C) __builtin_amdgcn_mfma_f32_16x16x32_bf16((A),(B),(C),0,0,0)

// ------------- zero padded-border of an NHWC buffer -------------
__global__ void zb_k(__hip_bfloat16* buf, int Cn) {
  int idx = blockIdx.x * 256 + threadIdx.x;
  int cg8 = Cn >> 3;
  int tot = NB * 772 * cg8;
  if (idx >= tot) return;
  int cg = idx % cg8; int rem = idx / cg8;
  int e = rem % 772; int b = rem / 772;
  int h, w2;
  if (e < 194) { h = 0; w2 = e; }
  else if (e < 388) { h = 193; w2 = e - 194; }
  else if (e < 580) { h = e - 388 + 1; w2 = 0; }
  else { h = e - 580 + 1; w2 = 193; }
  uint4 z = make_uint4(0, 0, 0, 0);
  *(uint4*)&buf[(((size_t)b * PH + h) * PH + w2) * Cn + cg * 8] = z;
}

// ------------- NCHW f32 -> padded NHWC bf16 (64-channel group) -------------
__global__ __launch_bounds__(256) void nchw2nhwc_k(const float* __restrict__ src,
    __hip_bfloat16* __restrict__ dst, int Cdst, int coff) {
  __shared__ float s[64][65];
  int p0 = blockIdx.x * 64; int b = blockIdx.y;
  int lane = threadIdx.x & 63, g = threadIdx.x >> 6;
#pragma unroll
  for (int i = 0; i < 16; ++i) {
    int c = i * 4 + g;
    s[c][lane] = src[((size_t)b * 64 + c) * HWSZ + p0 + lane];
  }
  __syncthreads();
  int h = p0 / WSZ, w0 = p0 - h * WSZ;
  size_t base = ((size_t)b * PH + h + 1) * PH + 1 + w0;
#pragma unroll
  for (int i = 0; i < 16; ++i) {
    int pp = i * 4 + g;
    dst[(base + pp) * Cdst + coff + lane] = __float2bfloat16(s[lane][pp]);
  }
}

// ------------- weight converters -------------
__global__ void convwt_k(const float* __restrict__ src, short* __restrict__ dst) {
  int idx = blockIdx.x * 256 + threadIdx.x;   // 36864
  int kk = idx >> 12, rem = idx & 4095;
  int co = rem >> 6, ci = rem & 63;
  dst[idx] = (short)f2bf(src[(co * 64 + ci) * 9 + kk]);
}
__global__ void omwt_k(const float* __restrict__ offw, const float* __restrict__ maskw,
                       const float* __restrict__ offb, const float* __restrict__ maskb,
                       short* __restrict__ dst, float* __restrict__ ob) {
  int idx = blockIdx.x * 256 + threadIdx.x;   // 36864 = 9*32*128
  int kk = idx >> 12, rem = idx & 4095;
  int co = rem >> 7, ci = rem & 127;
  float v = 0.f;
  if (co < 18) v = offw[(co * 128 + ci) * 9 + kk];
  else if (co < 27) v = maskw[((co - 18) * 128 + ci) * 9 + kk];
  dst[idx] = (short)f2bf(v);
  if (idx < 32) ob[idx] = idx < 18 ? offb[idx] : (idx < 27 ? maskb[idx - 18] : 0.f);
}
// deform weight -> [o][kk*64+ci] bf16
__global__ void dwtb_k(const float* __restrict__ dw, short* __restrict__ wtb) {
  int idx = blockIdx.x * 256 + threadIdx.x;   // 36864
  int o = idx / 576, rem = idx - o * 576;
  int kk = rem >> 6, ci = rem & 63;
  wtb[idx] = (short)f2bf(dw[(o * 64 + ci) * 9 + kk]);
}

// ------------- MFMA conv3x3 64->64 over padded NHWC bf16 -------------
template<int OUT_MODE, bool RELU>
__global__ __launch_bounds__(256, 2) void conv_mfma_k(
    const __hip_bfloat16* __restrict__ inp, const short* __restrict__ wt,
    const float* __restrict__ bias, __hip_bfloat16* __restrict__ outB, float* __restrict__ outF) {
  const int h = blockIdx.x, b = blockIdx.y;
  const int tid = threadIdx.x, lane = tid & 63, wid = tid >> 6;
  const int q = lane >> 4, r16 = lane & 15;
  __shared__ __align__(16) short tile[3 * 200 * 64];   // 76800 B

  {
    const char* gb = (const char*)(inp + ((size_t)b * PH + h) * (PH * 64));
    for (int s = wid; s < 75; s += 4) {
      int rr = s / 25, si = s - rr * 25;
      int pix = 8 * si + (lane >> 3);
      const char* src = gb + (size_t)rr * (PH * 128) + pix * 128
                      + ((((lane & 7) ^ ((lane >> 3) & 7))) << 4);
      GLDS(src, tile + rr * 12800 + si * 512);
    }
  }

  f32x4 acc[3][4];
  if (OUT_MODE == 0) {
#pragma unroll
    for (int nf = 0; nf < 4; ++nf) {
      float4 bv = *(const float4*)&bias[nf * 16 + q * 4];
      f32x4 v; v[0] = bv.x; v[1] = bv.y; v[2] = bv.z; v[3] = bv.w;
      acc[0][nf] = v; acc[1][nf] = v; acc[2][nf] = v;
    }
  } else {
#pragma unroll
    for (int nf = 0; nf < 4; ++nf) {
      float bs = bias[nf * 16 + r16];
      f32x4 v; v[0] = bs; v[1] = bs; v[2] = bs; v[3] = bs;
      acc[0][nf] = v; acc[1][nf] = v; acc[2][nf] = v;
    }
  }
  __syncthreads();

  const int wm0 = wid * 48;
  for (int kk = 0; kk < 9; ++kk) {
    const int ky = kk / 3, kx = kk - ky * 3;
    short8 bfr[2][4];
    const short* wk = wt + kk * 4096 + r16 * 64 + q * 8;
#pragma unroll
    for (int nf = 0; nf < 4; ++nf) {
      bfr[0][nf] = *(const short8*)(wk + nf * 1024);
      bfr[1][nf] = *(const short8*)(wk + nf * 1024 + 32);
    }
#pragma unroll
    for (int mf = 0; mf < 3; ++mf) {
      int pix = wm0 + mf * 16 + r16 + kx;
      const char* ab = (const char*)tile + ky * 25600 + pix * 128;
      int sw = (pix & 7) << 4;
      short8 a0 = *(const short8*)(ab + ((q << 4) ^ sw));
      short8 a1 = *(const short8*)(ab + (((q + 4) << 4) ^ sw));
#pragma unroll
      for (int nf = 0; nf < 4; ++nf) {
        if (OUT_MODE == 0) {
          acc[mf][nf] = MFMA(bfr[0][nf], a0, acc[mf][nf]);
          acc[mf][nf] = MFMA(bfr[1][nf], a1, acc[mf][nf]);
        } else {
          acc[mf][nf] = MFMA(a0, bfr[0][nf], acc[mf][nf]);
          acc[mf][nf] = MFMA(a1, bfr[1][nf], acc[mf][nf]);
        }
      }
    }
  }

  if (OUT_MODE == 0) {
    __syncthreads();
#pragma unroll
    for (int mf = 0; mf < 3; ++mf)
#pragma unroll
      for (int nf = 0; nf < 4; ++nf) {
        f32x4 v = acc[mf][nf];
        if (RELU) { v[0] = fmaxf(v[0], 0.f); v[1] = fmaxf(v[1], 0.f); v[2] = fmaxf(v[2], 0.f); v[3] = fmaxf(v[3], 0.f); }
        unsigned lo = (unsigned)f2bf(v[0]) | ((unsigned)f2bf(v[1]) << 16);
        unsigned hi = (unsigned)f2bf(v[2]) | ((unsigned)f2bf(v[3]) << 16);
        int pix = wm0 + mf * 16 + r16;
        int byteoff = (pix * 128 + nf * 32 + q * 8) ^ ((pix & 7) << 4);
        *(uint2*)((char*)tile + byteoff) = make_uint2(lo, hi);
      }
    __syncthreads();
    char* orow = (char*)outB + ((((size_t)b * PH + h + 1) * PH + 1) * 64) * 2;
    for (int s = wid; s < 24; s += 4) {
      int pix = 8 * s + (lane >> 3);
      int g16 = ((lane & 7) ^ (pix & 7)) << 4;
      uint4 d = *(const uint4*)((const char*)tile + pix * 128 + g16);
      *(uint4*)(orow + pix * 128 + ((lane & 7) << 4)) = d;
    }
  } else {
    float* ob2 = outF + (size_t)b * 64 * HWSZ + h * WSZ;
#pragma unroll
    for (int mf = 0; mf < 3; ++mf)
#pragma unroll
      for (int nf = 0; nf < 4; ++nf) {
        int pix0 = wm0 + mf * 16 + q * 4;
        int co = nf * 16 + r16;
        *(f32x4*)&ob2[(size_t)co * HWSZ + pix0] = acc[mf][nf];
      }
  }
}

// ------------- MFMA offset+mask conv: 128 -> 27(pad 32), NCHW f32 out -------------
__global__ __launch_bounds__(256, 3) void offmask_mfma_k(
    const __hip_bfloat16* __restrict__ cat, const short* __restrict__ wt2,
    const float* __restrict__ ob, float* __restrict__ om) {
  const int h = blockIdx.x, b = blockIdx.y;
  const int tid = threadIdx.x, lane = tid & 63, wid = tid >> 6;
  const int q = lane >> 4, r16 = lane & 15;
  __shared__ __align__(16) short tile[200 * 128];      // 51200 B

  f32x4 acc[3][2];
#pragma unroll
  for (int nf = 0; nf < 2; ++nf) {
    float bs = ob[nf * 16 + r16];
    f32x4 v; v[0] = bs; v[1] = bs; v[2] = bs; v[3] = bs;
    acc[0][nf] = v; acc[1][nf] = v; acc[2][nf] = v;
  }
  const char* gb = (const char*)(cat + ((size_t)b * PH + h) * (PH * 128));
  const int wm0 = wid * 48;

  for (int r = 0; r < 3; ++r) {
    __syncthreads();
    for (int s = wid; s < 50; s += 4) {
      int pix = 4 * s + (lane >> 4);
      const char* src = gb + (size_t)r * (PH * 256) + pix * 256
                      + ((((lane & 15) ^ (pix & 15))) << 4);
      GLDS(src, tile + s * 512);
    }
    __syncthreads();
    for (int kx = 0; kx < 3; ++kx) {
      int kk = r * 3 + kx;
      short8 bfr[4][2];
      const short* wk = wt2 + kk * 4096 + r16 * 128 + q * 8;
#pragma unroll
      for (int c4 = 0; c4 < 4; ++c4) {
        bfr[c4][0] = *(const short8*)(wk + c4 * 32);
        bfr[c4][1] = *(const short8*)(wk + 2048 + c4 * 32);
      }
#pragma unroll
      for (int mf = 0; mf < 3; ++mf) {
        int pix = wm0 + mf * 16 + r16 + kx;
        const char* ab = (const char*)tile + pix * 256;
        int sw = (pix & 15) << 4;
        short8 a0 = *(const short8*)(ab + ((q << 4) ^ sw));
        short8 a1 = *(const short8*)(ab + (((4 + q) << 4) ^ sw));
        short8 a2 = *(const short8*)(ab + (((8 + q) << 4) ^ sw));
        short8 a3 = *(const short8*)(ab + (((12 + q) << 4) ^ sw));
        acc[mf][0] = MFMA(a0, bfr[0][0], acc[mf][0]); acc[mf][1] = MFMA(a0, bfr[0][1], acc[mf][1]);
        acc[mf][0] = MFMA(a1, bfr[1][0], acc[mf][0]); acc[mf][1] = MFMA(a1, bfr[1][1], acc[mf][1]);
        acc[mf][0] = MFMA(a2, bfr[2][0], acc[mf][0]); acc[mf][1] = MFMA(a2, bfr[2][1], acc[mf][1]);
        acc[mf][0] = MFMA(a3, bfr[3][0], acc[mf][0]); acc[mf][1] = MFMA(a3, bfr[3][1], acc[mf][1]);
      }
    }
  }
#pragma unroll
  for (int mf = 0; mf < 3; ++mf)
#pragma unroll
    for (int nf = 0; nf < 2; ++nf) {
      int co = nf * 16 + r16;
      if (co < 27) {
        f32x4 v = acc[mf][nf];
        if (co >= 18) {
          v[0] = 2.f / (1.f + expf(-v[0])); v[1] = 2.f / (1.f + expf(-v[1]));
          v[2] = 2.f / (1.f + expf(-v[2])); v[3] = 2.f / (1.f + expf(-v[3]));
        }
        *(f32x4*)&om[((size_t)(b * 27 + co)) * HWSZ + h * WSZ + wm0 + mf * 16 + q * 4] = v;
      }
    }
}

// ------------- per (b,c) spatial mean over padded NHWC bf16 -------------
__global__ __launch_bounds__(256) void mean_k(const __hip_bfloat16* __restrict__ res, float* __restrict__ mean) {
  int blk = blockIdx.x;                 // 128 = 4 b * 32 slices
  int b = blk >> 5, slice = blk & 31;
  int c = threadIdx.x & 63, g = threadIdx.x >> 6;
  const __hip_bfloat16* rb = res + (size_t)b * PP * 64;
  float sum = 0.f;
  for (int i = g; i < 1152; i += 4) {
    int p = slice * 1152 + i;
    int hh = p / WSZ, ww = p - hh * WSZ;
    sum += bf2f(rb[((size_t)(hh + 1) * PH + ww + 1) * 64 + c]);
  }
  __shared__ float sm[4][64];
  sm[g][c] = sum; __syncthreads();
  if (threadIdx.x < 64)
    atomicAdd(&mean[b * 64 + threadIdx.x],
              (sm[0][threadIdx.x] + sm[1][threadIdx.x] + sm[2][threadIdx.x] + sm[3][threadIdx.x]) * (1.f / 36864.f));
}

// ------------- channel attention (tiny) -------------
__global__ void ca_k(const float* __restrict__ mean, const float* __restrict__ w1, const float* __restrict__ b1,
                     const float* __restrict__ w2, const float* __restrict__ b2, float* __restrict__ y) {
  __shared__ float s_m[4][64];
  __shared__ float s_t[4][4];
  int tid = threadIdx.x;
  int b = tid >> 6, c = tid & 63;
  s_m[b][c] = mean[tid];
  __syncthreads();
  if (tid < 16) {
    int bb = tid >> 2, r = tid & 3;
    float s = b1[r];
    for (int cc = 0; cc < 64; ++cc) s += w1[r * 64 + cc] * s_m[bb][cc];
    s_t[bb][r] = fmaxf(s, 0.f);
  }
  __syncthreads();
  float v = b2[c];
  for (int r = 0; r < 4; ++r) v += w2[c * 4 + r] * s_t[b][r];
  y[tid] = 1.f / (1.f + expf(-v));
}

// ------------- out1 = res*y + x (elementwise, padded NHWC bf16) -------------
__global__ __launch_bounds__(256) void out1_k(const __hip_bfloat16* __restrict__ res, const __hip_bfloat16* __restrict__ xn,
    const float* __restrict__ y, __hip_bfloat16* __restrict__ out1) {
  int idx = blockIdx.x * 256 + threadIdx.x;     // 4*36864*8
  int b = idx / 294912; int rem = idx - b * 294912;
  int p = rem >> 3, c8 = rem & 7;
  int hh = p / WSZ, ww = p - hh * WSZ;
  size_t off = ((size_t)b * PP + (size_t)(hh + 1) * PH + ww + 1) * 64 + c8 * 8;
  const __hip_bfloat16* rp = res + off;
  const __hip_bfloat16* xp = xn + off;
  __hip_bfloat16* op = out1 + off;
  const float* yb = y + b * 64 + c8 * 8;
  unsigned pk[4];
#pragma unroll
  for (int t = 0; t < 4; ++t) {
    float v0 = bf2f(rp[2 * t]) * yb[2 * t] + bf2f(xp[2 * t]);
    float v1 = bf2f(rp[2 * t + 1]) * yb[2 * t + 1] + bf2f(xp[2 * t + 1]);
    pk[t] = (unsigned)f2bf(v0) | ((unsigned)f2bf(v1) << 16);
  }
  *(uint4*)op = make_uint4(pk[0], pk[1], pk[2], pk[3]);
}

// ------------- deformable conv: bilinear sample -> bf16 A-tile -> MFMA GEMM -------------
__global__ __launch_bounds__(256, 3) void deform_mfma_k(
    const __hip_bfloat16* __restrict__ nhwc, const float* __restrict__ om,
    const short* __restrict__ wtb, __hip_bfloat16* __restrict__ fin) {
  int blk = blockIdx.x;            // NB * 1152, 32-pixel groups
  int b = blk / 1152;
  int p0 = (blk - b * 1152) * 32;
  int tid = threadIdx.x, lane = tid & 63, wid = tid >> 6;
  int q = lane >> 4, r16 = lane & 15;
  __shared__ __align__(16) short sA[32 * 576];      // 36864 B, row = pix (1152 B), XOR-swizzled
  __shared__ float s_bw[4][9][32];
  __shared__ int s_pk[9][32];

  const float* omb = om + (size_t)b * 27 * HWSZ + p0;
  // phase 1: bilinear corner weights + packed indices
  for (int e = tid; e < 288; e += 256) {
    int kk = e >> 5, pix = e & 31;
    int p = p0 + pix;
    int h = p / WSZ, w2 = p - h * WSZ;
    float oy = omb[(size_t)(2 * kk) * HWSZ + pix];
    float ox = omb[(size_t)(2 * kk + 1) * HWSZ + pix];
    float m2 = omb[(size_t)(18 + kk) * HWSZ + pix];
    float ys = (float)(h + kk / 3 - 1) + oy;
    float xs = (float)(w2 + kk % 3 - 1) + ox;
    float y0f = floorf(ys), x0f = floorf(xs);
    float wy1 = ys - y0f, wx1 = xs - x0f;
    float wy0 = 1.f - wy1, wx0 = 1.f - wx1;
    int y0 = (int)y0f, x0i = (int)x0f;
    int y1 = y0 + 1, x1 = x0i + 1;
    float vy0 = (y0 >= 0 && y0 < HSZ) ? 1.f : 0.f;
    float vx0 = (x0i >= 0 && x0i < WSZ) ? 1.f : 0.f;
    float vy1 = (y1 >= 0 && y1 < HSZ) ? 1.f : 0.f;
    float vx1 = (x1 >= 0 && x1 < WSZ) ? 1.f : 0.f;
    int y0c = min(max(y0, 0), HSZ - 1), x0c = min(max(x0i, 0), WSZ - 1);
    int y1c = min(max(y1, 0), HSZ - 1), x1c = min(max(x1, 0), WSZ - 1);
    s_bw[0][kk][pix] = wy0 * wx0 * m2 * vy0 * vx0;
    s_bw[1][kk][pix] = wy0 * wx1 * m2 * vy0 * vx1;
    s_bw[2][kk][pix] = wy1 * wx0 * m2 * vy1 * vx0;
    s_bw[3][kk][pix] = wy1 * wx1 * m2 * vy1 * vx1;
    s_pk[kk][pix] = ((((y0c + 1) * PH) + x0c + 1) << 2) | ((y1c - y0c) << 1) | (x1c - x0c);
  }
  __syncthreads();

  // phase 2: sample 4 channels x 4 taps per lane-task into bf16 A-tile
  const __hip_bfloat16* nb = nhwc + (size_t)b * PP * 64;
  for (int t = tid; t < 4608; t += 256) {     // 18 iterations
    int lg = t & 15, pair = t >> 4;
    int kk = pair >> 5, pix = pair & 31;
    float w00 = s_bw[0][kk][pix], w01 = s_bw[1][kk][pix];
    float w10 = s_bw[2][kk][pix], w11 = s_bw[3][kk][pix];
    int pk = s_pk[kk][pix];
    int i00 = pk >> 2, dy = (pk >> 1) & 1, dx = pk & 1;
    const __hip_bfloat16* g = nb + (size_t)i00 * 64 + lg * 4;
    uint2 A = *(const uint2*)g;
    uint2 Bv = *(const uint2*)(g + dx * 64);
    uint2 Cv = *(const uint2*)(g + dy * (PH * 64));
    uint2 Dv = *(const uint2*)(g + (dy * PH + dx) * 64);
    float v0 = w00 * bflo(A.x) + w01 * bflo(Bv.x) + w10 * bflo(Cv.x) + w11 * bflo(Dv.x);
    float v1 = w00 * bfhi(A.x) + w01 * bfhi(Bv.x) + w10 * bfhi(Cv.x) + w11 * bfhi(Dv.x);
    float v2 = w00 * bflo(A.y) + w01 * bflo(Bv.y) + w10 * bflo(Cv.y) + w11 * bflo(Dv.y);
    float v3 = w00 * bfhi(A.y) + w01 * bfhi(Bv.y) + w10 * bfhi(Cv.y) + w11 * bfhi(Dv.y);
    uint2 pkd = make_uint2((unsigned)f2bf(v0) | ((unsigned)f2bf(v1) << 16),
                           (unsigned)f2bf(v2) | ((unsigned)f2bf(v3) << 16));
    int off = (kk * 128 + lg * 8) ^ ((pix & 7) << 4);
    *(uint2*)((char*)sA + pix * 1152 + off) = pkd;
  }
  __syncthreads();

  // phase 3: GEMM 64co x 32pix x K576. Wave wid -> co slice [wid*16, wid*16+16)
  f32x4 acc[2];
  acc[0] = (f32x4){0.f, 0.f, 0.f, 0.f};
  acc[1] = (f32x4){0.f, 0.f, 0.f, 0.f};
  const short* wrow = wtb + (size_t)(wid * 16 + r16) * 576 + q * 8;
  const char* arow0 = (const char*)sA + r16 * 1152;
  const char* arow1 = (const char*)sA + (r16 + 16) * 1152;
  int sw = (r16 & 7) << 4;
  for (int ks = 0; ks < 18; ++ks) {
    short8 wf = *(const short8*)(wrow + ks * 32);
    int off0 = (ks * 64 + q * 16) ^ sw;
    short8 va = *(const short8*)(arow0 + off0);
    short8 vb = *(const short8*)(arow1 + off0);
    acc[0] = MFMA(wf, va, acc[0]);
    acc[1] = MFMA(wf, vb, acc[1]);
  }

  // epilogue: +out1 residual, pack bf16, NHWC store
  int h0 = p0 / WSZ, w0 = p0 - h0 * WSZ;
  size_t ro = ((size_t)(h0 + 1) * PH + w0 + 1) * 64;
  const __hip_bfloat16* resid = nb + ro;
  __hip_bfloat16* fp = fin + (size_t)b * PP * 64 + ro;
#pragma unroll
  for (int nf = 0; nf < 2; ++nf) {
    int pix = r16 + nf * 16;
    int co = wid * 16 + q * 4;
    const unsigned* rr = (const unsigned*)(resid + (size_t)pix * 64 + co);
    unsigned r0 = rr[0], r1 = rr[1];
    float o0 = acc[nf][0] + bflo(r0);
    float o1 = acc[nf][1] + bfhi(r0);
    float o2 = acc[nf][2] + bflo(r1);
    float o3 = acc[nf][3] + bfhi(r1);
    uint2 pk2 = make_uint2((unsigned)f2bf(o0) | ((unsigned)f2bf(o1) << 16),
                           (unsigned)f2bf(o2) | ((unsigned)f2bf(o3) << 16));
    *(uint2*)(fp + (size_t)pix * 64 + co) = pk2;
  }
}

extern "C" void kernel_launch(void* const* d_in, const int* in_sizes, int n_in,
                              void* d_out, int out_size, void* d_ws, size_t ws_size,
                              hipStream_t stream) {
  (void)in_sizes; (void)n_in; (void)out_size; (void)ws_size;
  const float* x     = (const float*)d_in[0];
  const float* inter = (const float*)d_in[1];
  const float* fea   = (const float*)d_in[2];
  const float* rw1   = (const float*)d_in[3];
  const float* rb1   = (const float*)d_in[4];
  const float* rw2   = (const float*)d_in[5];
  const float* rb2   = (const float*)d_in[6];
  const float* caw1  = (const float*)d_in[7];
  const float* cab1  = (const float*)d_in[8];
  const float* caw2  = (const float*)d_in[9];
  const float* cab2  = (const float*)d_in[10];
  const float* offw  = (const float*)d_in[11];
  const float* offb  = (const float*)d_in[12];
  const float* maskw = (const float*)d_in[13];
  const float* maskb = (const float*)d_in[14];
  const float* dw    = (const float*)d_in[15];
  const float* cw    = (const float*)d_in[16];
  const float* cb    = (const float*)d_in[17];

  char* w = (char*)d_ws;
  const size_t P64 = (size_t)NB * PP * 64 * 2 + 4096;
  const size_t PCAT = (size_t)NB * PP * 128 * 2 + 4096;
  __hip_bfloat16* xn   = (__hip_bfloat16*)(w);
  __hip_bfloat16* r1   = (__hip_bfloat16*)(w + P64);
  __hip_bfloat16* res  = (__hip_bfloat16*)(w + 2 * P64);
  __hip_bfloat16* out1 = (__hip_bfloat16*)(w + 3 * P64);
  __hip_bfloat16* cat  = (__hip_bfloat16*)(w + 4 * P64);
  char* tail = w + 4 * P64 + PCAT;
  short* wt1  = (short*)tail; tail += 73728;
  short* wt2c = (short*)tail; tail += 73728;
  short* wtf  = (short*)tail; tail += 73728;
  short* wtom = (short*)tail; tail += 73728;
  float* obb  = (float*)tail; tail += 128;
  short* wtb  = (short*)tail; tail += 73728;
  float* mean = (float*)tail; tail += 1024;
  float* yv   = (float*)tail; tail += 1024;
  float* omb  = (float*)res;        // overlay: om reuses res slot (res dead by then)
  __hip_bfloat16* fin = r1;         // overlay: fin reuses r1 slot (r1 dead by then)

  zb_k<<<(NB * 772 * 8 + 255) / 256, 256, 0, stream>>>(xn, 64);
  zb_k<<<(NB * 772 * 8 + 255) / 256, 256, 0, stream>>>(r1, 64);
  zb_k<<<(NB * 772 * 8 + 255) / 256, 256, 0, stream>>>(out1, 64);
  zb_k<<<(NB * 772 * 16 + 255) / 256, 256, 0, stream>>>(cat, 128);

  nchw2nhwc_k<<<dim3(576, 4), 256, 0, stream>>>(x, xn, 64, 0);
  nchw2nhwc_k<<<dim3(576, 4), 256, 0, stream>>>(inter, cat, 128, 0);
  nchw2nhwc_k<<<dim3(576, 4), 256, 0, stream>>>(fea, cat, 128, 64);
  convwt_k<<<144, 256, 0, stream>>>(rw1, wt1);
  convwt_k<<<144, 256, 0, stream>>>(rw2, wt2c);
  convwt_k<<<144, 256, 0, stream>>>(cw, wtf);
  omwt_k<<<144, 256, 0, stream>>>(offw, maskw, offb, maskb, wtom, obb);
  dwtb_k<<<144, 256, 0, stream>>>(dw, wtb);

  conv_mfma_k<0, true ><<<dim3(192, 4), 256, 0, stream>>>(xn, wt1, rb1, r1, nullptr);
  conv_mfma_k<0, false><<<dim3(192, 4), 256, 0, stream>>>(r1, wt2c, rb2, res, nullptr);
  hipMemsetAsync(mean, 0, 256 * 4, stream);
  mean_k<<<128, 256, 0, stream>>>(res, mean);
  ca_k<<<1, 256, 0, stream>>>(mean, caw1, cab1, caw2, cab2, yv);
  out1_k<<<4608, 256, 0, stream>>>(res, xn, yv, out1);
  offmask_mfma_k<<<dim3(192, 4), 256, 0, stream>>>(cat, wtom, obb, omb);
  deform_mfma_k<<<NB * 1152, 256, 0, stream>>>(out1, omb, wtb, fin);
  conv_mfma_k<1, false><<<dim3(192, 4), 256, 0, stream>>>(fin, wtf, cb, nullptr, (float*)d_out);
}

// Round 5
// 398.505 us; speedup vs baseline: 6.1566x; 1.0095x over previous
//
#include <hip/hip_runtime.h>
#include <hip/hip_bf16.h>
#include <hip/hip_fp16.h>
#include <math.h>

#define HSZ 192
#define WSZ 192
#define HWSZ (192*192)
#define PH 194                 // padded dim
#define PP (PH*PH)             // 37636 padded pixels
#define NB 4

typedef __attribute__((ext_vector_type(8))) short short8;
typedef __attribute__((ext_vector_type(4))) float f32x4;

__device__ inline unsigned short f2bf(float f) { __hip_bfloat16 h = __float2bfloat16(f); return *(unsigned short*)&h; }
__device__ inline float bf2f(__hip_bfloat16 h) { return __bfloat162float(h); }
__device__ inline float bflo(unsigned u) { return __uint_as_float(u << 16); }
__device__ inline float bfhi(unsigned u) { return __uint_as_float(u & 0xffff0000u); }

#define GLDS(SRC, DST) __builtin_amdgcn_global_load_lds( \
    (const __attribute__((address_space(1))) unsigned int*)(const void*)(SRC), \
    (__attribute__((address_space(3))) unsigned int*)(void*)(DST), 16, 0, 0)

#define MFMA(A,B,C) __builtin_amdgcn_mfma_f32_16x16x32_bf16((A),(B),(C),0,0,0)

// ------------- merged border-zero (4 buffers) -------------
__global__ void zb2_k(__hip_bfloat16* xn, __hip_bfloat16* r1, __hip_bfloat16* out1,
                      __hip_bfloat16* cat) {
  int job = blockIdx.y;
  __hip_bfloat16* buf = job == 0 ? xn : job == 1 ? r1 : job == 2 ? out1 : cat;
  int Cn = (job == 3) ? 128 : 64;
  int cg8 = Cn >> 3;
  int tot = NB * 772 * cg8;
  int idx = blockIdx.x * 256 + threadIdx.x;
  if (idx >= tot) return;
  int cg = idx % cg8; int rem = idx / cg8;
  int e = rem % 772; int b = rem / 772;
  int h, w2;
  if (e < 194) { h = 0; w2 = e; }
  else if (e < 388) { h = 193; w2 = e - 194; }
  else if (e < 580) { h = e - 388 + 1; w2 = 0; }
  else { h = e - 580 + 1; w2 = 193; }
  uint4 z = make_uint4(0, 0, 0, 0);
  *(uint4*)&buf[(((size_t)b * PH + h) * PH + w2) * Cn + cg * 8] = z;
}

// ------------- merged weight prep (5 jobs) + mean zero -------------
__global__ void wts_k(const float* __restrict__ rw1, const float* __restrict__ rw2,
                      const float* __restrict__ cw, const float* __restrict__ offw,
                      const float* __restrict__ maskw, const float* __restrict__ offb,
                      const float* __restrict__ maskb, const float* __restrict__ dwv,
                      short* wt1, short* wt2c, short* wtf, short* wtom, float* ob,
                      short* wtb, float* meanz) {
  int job = blockIdx.y;
  int idx = blockIdx.x * 256 + threadIdx.x;   // < 36864
  if (job < 3) {
    const float* src = job == 0 ? rw1 : job == 1 ? rw2 : cw;
    short* dst = job == 0 ? wt1 : job == 1 ? wt2c : wtf;
    int kk = idx >> 12, rem = idx & 4095;
    int co = rem >> 6, ci = rem & 63;
    dst[idx] = (short)f2bf(src[(co * 64 + ci) * 9 + kk]);
  } else if (job == 3) {
    int kk = idx >> 12, rem = idx & 4095;
    int co = rem >> 7, ci = rem & 127;
    float v = 0.f;
    if (co < 18) v = offw[(co * 128 + ci) * 9 + kk];
    else if (co < 27) v = maskw[((co - 18) * 128 + ci) * 9 + kk];
    wtom[idx] = (short)f2bf(v);
    if (idx < 32) ob[idx] = idx < 18 ? offb[idx] : (idx < 27 ? maskb[idx - 18] : 0.f);
  } else {
    int o = idx / 576, rem = idx - o * 576;
    int kk = rem >> 6, ci = rem & 63;
    wtb[idx] = (short)f2bf(dwv[(o * 64 + ci) * 9 + kk]);
    if (blockIdx.x == 0 && threadIdx.x < 256) meanz[threadIdx.x] = 0.f;
  }
}

// ------------- merged NCHW f32 -> padded NHWC bf16 (x -> xn, inter/fea -> cat) -------------
__global__ __launch_bounds__(256) void cvt_k(const float* __restrict__ x,
    const float* __restrict__ inter, const float* __restrict__ fea,
    __hip_bfloat16* __restrict__ xn, __hip_bfloat16* __restrict__ cat) {
  int job = blockIdx.z;
  const float* src = job == 0 ? x : job == 1 ? inter : fea;
  __hip_bfloat16* dst = job == 0 ? xn : cat;
  int Cdst = job == 0 ? 64 : 128;
  int coff = job == 2 ? 64 : 0;
  __shared__ float s[64][65];
  int p0 = blockIdx.x * 64; int b = blockIdx.y;
  int lane = threadIdx.x & 63, g = threadIdx.x >> 6;
#pragma unroll
  for (int i = 0; i < 16; ++i) {
    int c = i * 4 + g;
    s[c][lane] = src[((size_t)b * 64 + c) * HWSZ + p0 + lane];
  }
  __syncthreads();
  int pix = threadIdx.x >> 2, cg = threadIdx.x & 3;
  int h = p0 / WSZ, w0 = p0 - h * WSZ + pix;   // p0 64-aligned, 192=3*64 -> same row
  size_t addr = (((size_t)b * PH + h + 1) * PH + 1 + w0) * Cdst + coff + cg * 16;
  unsigned pk2[8];
#pragma unroll
  for (int t = 0; t < 8; ++t)
    pk2[t] = (unsigned)f2bf(s[cg * 16 + 2 * t][pix]) | ((unsigned)f2bf(s[cg * 16 + 2 * t + 1][pix]) << 16);
  *(uint4*)&dst[addr]     = make_uint4(pk2[0], pk2[1], pk2[2], pk2[3]);
  *(uint4*)&dst[addr + 8] = make_uint4(pk2[4], pk2[5], pk2[6], pk2[7]);
}

// ------------- MFMA conv3x3 64->64 over padded NHWC bf16 -------------
template<int OUT_MODE, bool RELU>
__global__ __launch_bounds__(256, 2) void conv_mfma_k(
    const __hip_bfloat16* __restrict__ inp, const short* __restrict__ wt,
    const float* __restrict__ bias, __hip_bfloat16* __restrict__ outB, float* __restrict__ outF) {
  const int h = blockIdx.x, b = blockIdx.y;
  const int tid = threadIdx.x, lane = tid & 63, wid = tid >> 6;
  const int q = lane >> 4, r16 = lane & 15;
  __shared__ __align__(16) short tile[3 * 200 * 64];   // 76800 B

  {
    const char* gb = (const char*)(inp + ((size_t)b * PH + h) * (PH * 64));
    for (int s = wid; s < 75; s += 4) {
      int rr = s / 25, si = s - rr * 25;
      int pix = 8 * si + (lane >> 3);
      const char* src = gb + (size_t)rr * (PH * 128) + pix * 128
                      + ((((lane & 7) ^ ((lane >> 3) & 7))) << 4);
      GLDS(src, tile + rr * 12800 + si * 512);
    }
  }

  f32x4 acc[3][4];
  if (OUT_MODE == 0) {
#pragma unroll
    for (int nf = 0; nf < 4; ++nf) {
      float4 bv = *(const float4*)&bias[nf * 16 + q * 4];
      f32x4 v; v[0] = bv.x; v[1] = bv.y; v[2] = bv.z; v[3] = bv.w;
      acc[0][nf] = v; acc[1][nf] = v; acc[2][nf] = v;
    }
  } else {
#pragma unroll
    for (int nf = 0; nf < 4; ++nf) {
      float bs = bias[nf * 16 + r16];
      f32x4 v; v[0] = bs; v[1] = bs; v[2] = bs; v[3] = bs;
      acc[0][nf] = v; acc[1][nf] = v; acc[2][nf] = v;
    }
  }
  __syncthreads();

  const int wm0 = wid * 48;
  for (int kk = 0; kk < 9; ++kk) {
    const int ky = kk / 3, kx = kk - ky * 3;
    short8 bfr[2][4];
    const short* wk = wt + kk * 4096 + r16 * 64 + q * 8;
#pragma unroll
    for (int nf = 0; nf < 4; ++nf) {
      bfr[0][nf] = *(const short8*)(wk + nf * 1024);
      bfr[1][nf] = *(const short8*)(wk + nf * 1024 + 32);
    }
#pragma unroll
    for (int mf = 0; mf < 3; ++mf) {
      int pix = wm0 + mf * 16 + r16 + kx;
      const char* ab = (const char*)tile + ky * 25600 + pix * 128;
      int sw = (pix & 7) << 4;
      short8 a0 = *(const short8*)(ab + ((q << 4) ^ sw));
      short8 a1 = *(const short8*)(ab + (((q + 4) << 4) ^ sw));
#pragma unroll
      for (int nf = 0; nf < 4; ++nf) {
        if (OUT_MODE == 0) {
          acc[mf][nf] = MFMA(bfr[0][nf], a0, acc[mf][nf]);
          acc[mf][nf] = MFMA(bfr[1][nf], a1, acc[mf][nf]);
        } else {
          acc[mf][nf] = MFMA(a0, bfr[0][nf], acc[mf][nf]);
          acc[mf][nf] = MFMA(a1, bfr[1][nf], acc[mf][nf]);
        }
      }
    }
  }

  if (OUT_MODE == 0) {
    __syncthreads();
#pragma unroll
    for (int mf = 0; mf < 3; ++mf)
#pragma unroll
      for (int nf = 0; nf < 4; ++nf) {
        f32x4 v = acc[mf][nf];
        if (RELU) { v[0] = fmaxf(v[0], 0.f); v[1] = fmaxf(v[1], 0.f); v[2] = fmaxf(v[2], 0.f); v[3] = fmaxf(v[3], 0.f); }
        unsigned lo = (unsigned)f2bf(v[0]) | ((unsigned)f2bf(v[1]) << 16);
        unsigned hi = (unsigned)f2bf(v[2]) | ((unsigned)f2bf(v[3]) << 16);
        int pix = wm0 + mf * 16 + r16;
        int byteoff = (pix * 128 + nf * 32 + q * 8) ^ ((pix & 7) << 4);
        *(uint2*)((char*)tile + byteoff) = make_uint2(lo, hi);
      }
    __syncthreads();
    char* orow = (char*)outB + ((((size_t)b * PH + h + 1) * PH + 1) * 64) * 2;
    for (int s = wid; s < 24; s += 4) {
      int pix = 8 * s + (lane >> 3);
      int g16 = ((lane & 7) ^ (pix & 7)) << 4;
      uint4 d = *(const uint4*)((const char*)tile + pix * 128 + g16);
      *(uint4*)(orow + pix * 128 + ((lane & 7) << 4)) = d;
    }
  } else {
    float* ob2 = outF + (size_t)b * 64 * HWSZ + h * WSZ;
#pragma unroll
    for (int mf = 0; mf < 3; ++mf)
#pragma unroll
      for (int nf = 0; nf < 4; ++nf) {
        int pix0 = wm0 + mf * 16 + q * 4;
        int co = nf * 16 + r16;
        *(f32x4*)&ob2[(size_t)co * HWSZ + pix0] = acc[mf][nf];
      }
  }
}

// ------------- MFMA offset+mask conv: 128 -> 27(pad 32), NCHW f32 out -------------
__global__ __launch_bounds__(256, 3) void offmask_mfma_k(
    const __hip_bfloat16* __restrict__ cat, const short* __restrict__ wt2,
    const float* __restrict__ ob, float* __restrict__ om) {
  const int h = blockIdx.x, b = blockIdx.y;
  const int tid = threadIdx.x, lane = tid & 63, wid = tid >> 6;
  const int q = lane >> 4, r16 = lane & 15;
  __shared__ __align__(16) short tile[200 * 128];      // 51200 B

  f32x4 acc[3][2];
#pragma unroll
  for (int nf = 0; nf < 2; ++nf) {
    float bs = ob[nf * 16 + r16];
    f32x4 v; v[0] = bs; v[1] = bs; v[2] = bs; v[3] = bs;
    acc[0][nf] = v; acc[1][nf] = v; acc[2][nf] = v;
  }
  const char* gb = (const char*)(cat + ((size_t)b * PH + h) * (PH * 128));
  const int wm0 = wid * 48;

  for (int r = 0; r < 3; ++r) {
    __syncthreads();
    for (int s = wid; s < 50; s += 4) {
      int pix = 4 * s + (lane >> 4);
      const char* src = gb + (size_t)r * (PH * 256) + pix * 256
                      + ((((lane & 15) ^ (pix & 15))) << 4);
      GLDS(src, tile + s * 512);
    }
    __syncthreads();
    for (int kx = 0; kx < 3; ++kx) {
      int kk = r * 3 + kx;
      short8 bfr[4][2];
      const short* wk = wt2 + kk * 4096 + r16 * 128 + q * 8;
#pragma unroll
      for (int c4 = 0; c4 < 4; ++c4) {
        bfr[c4][0] = *(const short8*)(wk + c4 * 32);
        bfr[c4][1] = *(const short8*)(wk + 2048 + c4 * 32);
      }
#pragma unroll
      for (int mf = 0; mf < 3; ++mf) {
        int pix = wm0 + mf * 16 + r16 + kx;
        const char* ab = (const char*)tile + pix * 256;
        int sw = (pix & 15) << 4;
        short8 a0 = *(const short8*)(ab + ((q << 4) ^ sw));
        short8 a1 = *(const short8*)(ab + (((4 + q) << 4) ^ sw));
        short8 a2 = *(const short8*)(ab + (((8 + q) << 4) ^ sw));
        short8 a3 = *(const short8*)(ab + (((12 + q) << 4) ^ sw));
        acc[mf][0] = MFMA(a0, bfr[0][0], acc[mf][0]); acc[mf][1] = MFMA(a0, bfr[0][1], acc[mf][1]);
        acc[mf][0] = MFMA(a1, bfr[1][0], acc[mf][0]); acc[mf][1] = MFMA(a1, bfr[1][1], acc[mf][1]);
        acc[mf][0] = MFMA(a2, bfr[2][0], acc[mf][0]); acc[mf][1] = MFMA(a2, bfr[2][1], acc[mf][1]);
        acc[mf][0] = MFMA(a3, bfr[3][0], acc[mf][0]); acc[mf][1] = MFMA(a3, bfr[3][1], acc[mf][1]);
      }
    }
  }
#pragma unroll
  for (int mf = 0; mf < 3; ++mf)
#pragma unroll
    for (int nf = 0; nf < 2; ++nf) {
      int co = nf * 16 + r16;
      if (co < 27) {
        f32x4 v = acc[mf][nf];
        if (co >= 18) {
          v[0] = 2.f / (1.f + expf(-v[0])); v[1] = 2.f / (1.f + expf(-v[1]));
          v[2] = 2.f / (1.f + expf(-v[2])); v[3] = 2.f / (1.f + expf(-v[3]));
        }
        *(f32x4*)&om[((size_t)(b * 27 + co)) * HWSZ + h * WSZ + wm0 + mf * 16 + q * 4] = v;
      }
    }
}

// ------------- per (b,c) spatial mean over padded NHWC bf16 -------------
__global__ __launch_bounds__(256) void mean_k(const __hip_bfloat16* __restrict__ res, float* __restrict__ mean) {
  int blk = blockIdx.x;                 // 128 = 4 b * 32 slices
  int b = blk >> 5, slice = blk & 31;
  int c = threadIdx.x & 63, g = threadIdx.x >> 6;
  const __hip_bfloat16* rb = res + (size_t)b * PP * 64;
  float sum = 0.f;
  for (int i = g; i < 1152; i += 4) {
    int p = slice * 1152 + i;
    int hh = p / WSZ, ww = p - hh * WSZ;
    sum += bf2f(rb[((size_t)(hh + 1) * PH + ww + 1) * 64 + c]);
  }
  __shared__ float sm[4][64];
  sm[g][c] = sum; __syncthreads();
  if (threadIdx.x < 64)
    atomicAdd(&mean[b * 64 + threadIdx.x],
              (sm[0][threadIdx.x] + sm[1][threadIdx.x] + sm[2][threadIdx.x] + sm[3][threadIdx.x]) * (1.f / 36864.f));
}

// ------------- channel attention (tiny) -------------
__global__ void ca_k(const float* __restrict__ mean, const float* __restrict__ w1, const float* __restrict__ b1,
                     const float* __restrict__ w2, const float* __restrict__ b2, float* __restrict__ y) {
  __shared__ float s_m[4][64];
  __shared__ float s_t[4][4];
  int tid = threadIdx.x;
  int b = tid >> 6, c = tid & 63;
  s_m[b][c] = mean[tid];
  __syncthreads();
  if (tid < 16) {
    int bb = tid >> 2, r = tid & 3;
    float s = b1[r];
    for (int cc = 0; cc < 64; ++cc) s += w1[r * 64 + cc] * s_m[bb][cc];
    s_t[bb][r] = fmaxf(s, 0.f);
  }
  __syncthreads();
  float v = b2[c];
  for (int r = 0; r < 4; ++r) v += w2[c * 4 + r] * s_t[b][r];
  y[tid] = 1.f / (1.f + expf(-v));
}

// ------------- out1 = res*y + x (elementwise, padded NHWC bf16) -------------
__global__ __launch_bounds__(256) void out1_k(const __hip_bfloat16* __restrict__ res, const __hip_bfloat16* __restrict__ xn,
    const float* __restrict__ y, __hip_bfloat16* __restrict__ out1) {
  int idx = blockIdx.x * 256 + threadIdx.x;     // 4*36864*8
  int b = idx / 294912; int rem = idx - b * 294912;
  int p = rem >> 3, c8 = rem & 7;
  int hh = p / WSZ, ww = p - hh * WSZ;
  size_t off = ((size_t)b * PP + (size_t)(hh + 1) * PH + ww + 1) * 64 + c8 * 8;
  const __hip_bfloat16* rp = res + off;
  const __hip_bfloat16* xp = xn + off;
  __hip_bfloat16* op = out1 + off;
  const float* yb = y + b * 64 + c8 * 8;
  unsigned pk[4];
#pragma unroll
  for (int t = 0; t < 4; ++t) {
    float v0 = bf2f(rp[2 * t]) * yb[2 * t] + bf2f(xp[2 * t]);
    float v1 = bf2f(rp[2 * t + 1]) * yb[2 * t + 1] + bf2f(xp[2 * t + 1]);
    pk[t] = (unsigned)f2bf(v0) | ((unsigned)f2bf(v1) << 16);
  }
  *(uint4*)op = make_uint4(pk[0], pk[1], pk[2], pk[3]);
}

// ------------- deformable conv: kk-sliced double-buffered sample+MFMA pipeline -------------
__global__ __launch_bounds__(256) void deform_mfma_k(
    const __hip_bfloat16* __restrict__ nhwc, const float* __restrict__ om,
    const short* __restrict__ wtb, __hip_bfloat16* __restrict__ fin) {
  int blk = blockIdx.x;            // NB * 1152, 32-pixel groups
  int b = blk / 1152;
  int p0 = (blk - b * 1152) * 32;
  int tid = threadIdx.x, lane = tid & 63, wid = tid >> 6;
  int q = lane >> 4, r16 = lane & 15;
  __shared__ __align__(16) short sA[2][32][64];   // 8192 B total; buf stride 4096 B; rows 128 B XOR-swizzled
  __shared__ __half2 s_bw[2][9][32];              // (w00,w01),(w10,w11)
  __shared__ int s_pk[9][32];

  const float* omb = om + (size_t)b * 27 * HWSZ + p0;
  // phase 1: bilinear corner weights + packed indices
  for (int e = tid; e < 288; e += 256) {
    int kk = e >> 5, pix = e & 31;
    int p = p0 + pix;
    int h = p / WSZ, w2 = p - h * WSZ;
    float oy = omb[(size_t)(2 * kk) * HWSZ + pix];
    float ox = omb[(size_t)(2 * kk + 1) * HWSZ + pix];
    float m2 = omb[(size_t)(18 + kk) * HWSZ + pix];
    float ys = (float)(h + kk / 3 - 1) + oy;
    float xs = (float)(w2 + kk % 3 - 1) + ox;
    float y0f = floorf(ys), x0f = floorf(xs);
    float wy1 = ys - y0f, wx1 = xs - x0f;
    float wy0 = 1.f - wy1, wx0 = 1.f - wx1;
    int y0 = (int)y0f, x0i = (int)x0f;
    int y1 = y0 + 1, x1 = x0i + 1;
    float vy0 = (y0 >= 0 && y0 < HSZ) ? 1.f : 0.f;
    float vx0 = (x0i >= 0 && x0i < WSZ) ? 1.f : 0.f;
    float vy1 = (y1 >= 0 && y1 < HSZ) ? 1.f : 0.f;
    float vx1 = (x1 >= 0 && x1 < WSZ) ? 1.f : 0.f;
    int y0c = min(max(y0, 0), HSZ - 1), x0c = min(max(x0i, 0), WSZ - 1);
    int y1c = min(max(y1, 0), HSZ - 1), x1c = min(max(x1, 0), WSZ - 1);
    s_bw[0][kk][pix] = __floats2half2_rn(wy0 * wx0 * m2 * vy0 * vx0, wy0 * wx1 * m2 * vy0 * vx1);
    s_bw[1][kk][pix] = __floats2half2_rn(wy1 * wx0 * m2 * vy1 * vx0, wy1 * wx1 * m2 * vy1 * vx1);
    s_pk[kk][pix] = ((((y0c + 1) * PH) + x0c + 1) << 2) | ((y1c - y0c) << 1) | (x1c - x0c);
  }
  __syncthreads();

  const __hip_bfloat16* nb = nhwc + (size_t)b * PP * 64;
  const int spix = tid & 31, lg = tid >> 5;          // sampling task: 8 ch @ pixel spix
  const int swz = (spix & 7) << 4;
  const int rsw = (r16 & 7) << 4;

  uint4 A, B, C, D; float2 wab, wcd;
#define ISSUE(KK) do { \
    float2 w0_ = __half22float2(s_bw[0][KK][spix]); \
    float2 w1_ = __half22float2(s_bw[1][KK][spix]); \
    wab = w0_; wcd = w1_; \
    int pk_ = s_pk[KK][spix]; \
    int i00_ = pk_ >> 2, dy_ = (pk_ >> 1) & 1, dx_ = pk_ & 1; \
    const __hip_bfloat16* g_ = nb + (size_t)i00_ * 64 + lg * 8; \
    A = *(const uint4*)g_; \
    B = *(const uint4*)(g_ + dx_ * 64); \
    C = *(const uint4*)(g_ + dy_ * (PH * 64)); \
    D = *(const uint4*)(g_ + (dy_ * PH + dx_) * 64); \
  } while (0)
#define CSTORE(BUF) do { \
    const unsigned* ap_ = (const unsigned*)&A; const unsigned* bp_ = (const unsigned*)&B; \
    const unsigned* cp_ = (const unsigned*)&C; const unsigned* dp_ = (const unsigned*)&D; \
    unsigned o_[4]; \
    _Pragma("unroll") \
    for (int j_ = 0; j_ < 4; ++j_) { \
      float lo_ = wab.x * bflo(ap_[j_]) + wab.y * bflo(bp_[j_]) + wcd.x * bflo(cp_[j_]) + wcd.y * bflo(dp_[j_]); \
      float hi_ = wab.x * bfhi(ap_[j_]) + wab.y * bfhi(bp_[j_]) + wcd.x * bfhi(cp_[j_]) + wcd.y * bfhi(dp_[j_]); \
      o_[j_] = (unsigned)f2bf(lo_) | ((unsigned)f2bf(hi_) << 16); \
    } \
    *(uint4*)((char*)&sA[BUF][spix][0] + ((lg * 16) ^ swz)) = make_uint4(o_[0], o_[1], o_[2], o_[3]); \
  } while (0)

  // prologue: sample kk=0 into buf 0
  ISSUE(0);
  CSTORE(0);

  f32x4 acc0 = (f32x4){0.f, 0.f, 0.f, 0.f};
  f32x4 acc1 = (f32x4){0.f, 0.f, 0.f, 0.f};
  const short* wrow = wtb + (size_t)(wid * 16 + r16) * 576;
  const char* a0base = (const char*)&sA[0][0][0] + r16 * 128;
  const char* a1base = (const char*)&sA[0][0][0] + (r16 + 16) * 128;

  for (int kk = 0; kk < 9; ++kk) {
    int cur = kk & 1;
    if (kk < 8) ISSUE(kk + 1);           // gathers in flight across barrier region
    __syncthreads();                     // slice kk visible to all
#pragma unroll
    for (int s = 0; s < 2; ++s) {
      short8 wf = *(const short8*)(wrow + kk * 64 + s * 32 + q * 8);
      int off = (cur * 4096) + ((s * 64 + q * 16) ^ rsw);   // FIX: buf stride is 4096 B
      short8 va = *(const short8*)(a0base + off);
      short8 vb = *(const short8*)(a1base + off);
      acc0 = MFMA(wf, va, acc0);
      acc1 = MFMA(wf, vb, acc1);
    }
    if (kk < 8) CSTORE(cur ^ 1);         // write next slice (other buffer)
  }

  // epilogue: +out1 residual, pack bf16, NHWC store
  int h0 = p0 / WSZ, w0 = p0 - h0 * WSZ;
  size_t ro = ((size_t)(h0 + 1) * PH + w0 + 1) * 64;
  const __hip_bfloat16* resid = nb + ro;
  __hip_bfloat16* fp = fin + (size_t)b * PP * 64 + ro;
#pragma unroll
  for (int nf = 0; nf < 2; ++nf) {
    f32x4 av = nf ? acc1 : acc0;
    int pix = r16 + nf * 16;
    int co = wid * 16 + q * 4;
    const unsigned* rr = (const unsigned*)(resid + (size_t)pix * 64 + co);
    unsigned r0 = rr[0], r1 = rr[1];
    float o0 = av[0] + bflo(r0);
    float o1 = av[1] + bfhi(r0);
    float o2 = av[2] + bflo(r1);
    float o3 = av[3] + bfhi(r1);
    uint2 pk2 = make_uint2((unsigned)f2bf(o0) | ((unsigned)f2bf(o1) << 16),
                           (unsigned)f2bf(o2) | ((unsigned)f2bf(o3) << 16));
    *(uint2*)(fp + (size_t)pix * 64 + co) = pk2;
  }
#undef ISSUE
#undef CSTORE
}

extern "C" void kernel_launch(void* const* d_in, const int* in_sizes, int n_in,
                              void* d_out, int out_size, void* d_ws, size_t ws_size,
                              hipStream_t stream) {
  (void)in_sizes; (void)n_in; (void)out_size; (void)ws_size;
  const float* x     = (const float*)d_in[0];
  const float* inter = (const float*)d_in[1];
  const float* fea   = (const float*)d_in[2];
  const float* rw1   = (const float*)d_in[3];
  const float* rb1   = (const float*)d_in[4];
  const float* rw2   = (const float*)d_in[5];
  const float* rb2   = (const float*)d_in[6];
  const float* caw1  = (const float*)d_in[7];
  const float* cab1  = (const float*)d_in[8];
  const float* caw2  = (const float*)d_in[9];
  const float* cab2  = (const float*)d_in[10];
  const float* offw  = (const float*)d_in[11];
  const float* offb  = (const float*)d_in[12];
  const float* maskw = (const float*)d_in[13];
  const float* maskb = (const float*)d_in[14];
  const float* dw    = (const float*)d_in[15];
  const float* cw    = (const float*)d_in[16];
  const float* cb    = (const float*)d_in[17];

  char* w = (char*)d_ws;
  const size_t P64 = (size_t)NB * PP * 64 * 2 + 4096;
  const size_t PCAT = (size_t)NB * PP * 128 * 2 + 4096;
  __hip_bfloat16* xn   = (__hip_bfloat16*)(w);
  __hip_bfloat16* r1   = (__hip_bfloat16*)(w + P64);
  __hip_bfloat16* res  = (__hip_bfloat16*)(w + 2 * P64);
  __hip_bfloat16* out1 = (__hip_bfloat16*)(w + 3 * P64);
  __hip_bfloat16* cat  = (__hip_bfloat16*)(w + 4 * P64);
  char* tail = w + 4 * P64 + PCAT;
  short* wt1  = (short*)tail; tail += 73728;
  short* wt2c = (short*)tail; tail += 73728;
  short* wtf  = (short*)tail; tail += 73728;
  short* wtom = (short*)tail; tail += 73728;
  float* obb  = (float*)tail; tail += 128;
  short* wtb  = (short*)tail; tail += 73728;
  float* mean = (float*)tail; tail += 1024;
  float* yv   = (float*)tail; tail += 1024;
  float* omb  = (float*)res;        // overlay: om reuses res slot (res dead by then)
  __hip_bfloat16* fin = r1;         // overlay: fin reuses r1 slot (r1 dead by then)

  zb2_k<<<dim3(194, 4), 256, 0, stream>>>(xn, r1, out1, cat);
  wts_k<<<dim3(144, 5), 256, 0, stream>>>(rw1, rw2, cw, offw, maskw, offb, maskb, dw,
                                          wt1, wt2c, wtf, wtom, obb, wtb, mean);
  cvt_k<<<dim3(576, 4, 3), 256, 0, stream>>>(x, inter, fea, xn, cat);

  conv_mfma_k<0, true ><<<dim3(192, 4), 256, 0, stream>>>(xn, wt1, rb1, r1, nullptr);
  conv_mfma_k<0, false><<<dim3(192, 4), 256, 0, stream>>>(r1, wt2c, rb2, res, nullptr);
  mean_k<<<128, 256, 0, stream>>>(res, mean);
  ca_k<<<1, 256, 0, stream>>>(mean, caw1, cab1, caw2, cab2, yv);
  out1_k<<<4608, 256, 0, stream>>>(res, xn, yv, out1);
  offmask_mfma_k<<<dim3(192, 4), 256, 0, stream>>>(cat, wtom, obb, omb);
  deform_mfma_k<<<NB * 1152, 256, 0, stream>>>(out1, omb, wtb, fin);
  conv_mfma_k<1, false><<<dim3(192, 4), 256, 0, stream>>>(fin, wtf, cb, nullptr, (float*)d_out);
}